// Round 12
// baseline (3600.727 us; speedup 1.0000x reference)
//
#include <hip/hip_runtime.h>
#include <hip/hip_bf16.h>

// PointNetMSG on MI355X. Inputs FP32, output FP32. Internal fp32, ws bf16.
// B=4, N=16384, Cs=32, M=1024, scales: (r=0.1,k=32),(r=0.2,k=64).
// R12: (1) fps: per-wave slot ownership — each wave polls 2 slots and
// prefetches those candidates' features into LDS while waiting for
// stragglers; winner-select runs from LDS (removes serial post-detect
// gather + full-set poll cadence). Frame otherwise identical to R11.
// (2) tail: conv1 stores z1 (f32) when ws allows -> write pass is
// elementwise; bnfin folded into conv1 kernels (bit-identical math).

static constexpr int Bb = 4;
static constexpr int Npts = 16384;
static constexpr int Mc = 1024;
static constexpr int NBLK = 16;                      // fps blocks per batch
static constexpr int OUT_EXPECT = 12288 + 1048576;   // new_xyz + feats
#define BN_EPS 1e-5f
#define SLOPE 0.02f
#define SCOPE_AGT __HIP_MEMORY_SCOPE_AGENT

// ---- workspace layout (base 1,687,552 B proven; z1 path needs 3,784,704) ----
static constexpr size_t OFF_STATS = 33024;    // f32 [2][384]
static constexpr size_t ZERO_BYTES = 65536;
static constexpr size_t OFF_CIDX  = 65536;    // i32 [4][1024]
static constexpr size_t OFF_IDX0  = 81920;    // u16 [4][1024][32]
static constexpr size_t OFF_CNT0  = 344064;   // i32 [4][1024]
static constexpr size_t OFF_IDX1  = 360448;   // u16 [4][1024][64]
static constexpr size_t OFF_CNT1  = 884736;   // i32 [4][1024]
static constexpr size_t OFF_ATTN  = 901120;   // bf16 [4][32][1024]
static constexpr size_t OFF_Z0    = 1163264;  // bf16 [4][64][1024]
static constexpr size_t WS_REQUIRED = 1687552;
// fps val slots u64[4][1024][16] = 524288 B, aliased over attn/z0 (fps-only lifetime)
static constexpr size_t OFF_FSLOT = 901120;
static constexpr size_t FSLOT_BYTES = (size_t)Bb * Mc * NBLK * 8;
// optional z1 f32 [4][128][1024] = 2 MB beyond base layout (runtime-gated)
static constexpr size_t OFF_Z1 = 1687552;
static constexpr size_t WS_Z1_REQUIRED = OFF_Z1 + (size_t)Bb * 128 * Mc * 4;

__device__ __forceinline__ float sup_at(const float* xyz, const float* pf,
                                        int b, int c, int n) {
  return (c < 3) ? xyz[((size_t)b*3 + c)*Npts + n]
                 : pf[((size_t)b*29 + (c-3))*Npts + n];
}

__device__ __forceinline__ float sanf(float v, float repl) {
  if (!(v == v) || fabsf(v) > 1e30f) v = repl;
  return v;
}

__global__ __launch_bounds__(256) void fill_kernel(float* out, int n, float val) {
  int i = blockIdx.x * 256 + threadIdx.x;
  if (i < n) out[i] = val;
}

// ---- K1: FPS v7. 16 blocks x 512 threads per batch, 2 pts/thread in VGPRs.
// Distance arithmetic bit-identical to R6-R11 (sequential __fadd_rn chain).
__global__ __launch_bounds__(512, 2) void fps_kernel(
    const float* __restrict__ xyz, const float* __restrict__ pf,
    int* __restrict__ cidx, unsigned long long* __restrict__ slots) {
  const int blk = blockIdx.x;
  const int b = blk >> 4;
  const int sb = blk & (NBLK - 1);
  const int tid = threadIdx.x;
  const int lane = tid & 63, wid = tid >> 6;
  float f0[32], f1[32];
  const int p0 = sb * 1024 + tid;
  const int p1 = p0 + 512;
  float d0 = 1e10f, d1 = 1e10f;
#pragma unroll
  for (int c = 0; c < 32; ++c) {
    f0[c] = sup_at(xyz, pf, b, c, p0);
    f1[c] = sup_at(xyz, pf, b, c, p1);
  }
  __shared__ float cf[32];
  __shared__ float cand[NBLK][32];
  __shared__ unsigned long long red[8];
  __shared__ unsigned long long cval[NBLK];
  if (sb == 0 && tid == 0) cidx[b * Mc] = 0;
  if (tid < 32) cf[tid] = sup_at(xyz, pf, b, tid, 0);   // centroid 0 = point 0
  __syncthreads();
  unsigned long long* slotb = slots + (size_t)b * Mc * NBLK;
  for (int it = 0; it < Mc - 1; ++it) {
    // ---- local distance update (exact R6 arithmetic) ----
    float cc[32];
#pragma unroll
    for (int c = 0; c < 32; ++c) cc[c] = cf[c];
    {
      float d = 0.f, e = 0.f;
#pragma unroll
      for (int c = 0; c < 32; ++c) {
        float t0 = f0[c] - cc[c];
        float s0 = __fmul_rn(t0, t0);
        d = (c == 0) ? s0 : __fadd_rn(d, s0);
        float t1 = f1[c] - cc[c];
        float s1 = __fmul_rn(t1, t1);
        e = (c == 0) ? s1 : __fadd_rn(e, s1);
      }
      d0 = fminf(d0, d);
      d1 = fminf(d1, e);
    }
    float bd; int bp;
    if (d0 >= d1) { bd = d0; bp = p0; } else { bd = d1; bp = p1; }  // p0<p1: first-index tiebreak
    unsigned long long v =
        ((unsigned long long)__float_as_uint(bd) << 32) | (unsigned int)(~(unsigned int)bp);
#pragma unroll
    for (int d = 32; d; d >>= 1) {
      unsigned long long o = __shfl_xor(v, d, 64);
      if (o > v) v = o;
    }
    if (lane == 0) red[wid] = v;
    __syncthreads();
    if (tid == 0) {
      unsigned long long vb = red[0];
#pragma unroll
      for (int w = 1; w < 8; ++w) if (red[w] > vb) vb = red[w];
      atomicMax(&slotb[(size_t)it * NBLK + sb], vb);   // single publish, val != 0 always
    }
    // ---- per-wave: poll 2 owned slots; prefetch their candidates into LDS
    // as soon as each arrives (overlaps the straggler wait) ----
    {
      const int myslot = (wid << 1) | (lane >> 5);
      const unsigned long long* sp = &slotb[(size_t)it * NBLK + myslot];
      unsigned long long myv;
      while ((myv = __hip_atomic_load(sp, __ATOMIC_RELAXED, SCOPE_AGT)) == 0ull)
        __builtin_amdgcn_s_sleep(1);
      int pc = (int)(~(unsigned int)(myv & 0xffffffffu)) & (Npts - 1);
      cand[myslot][lane & 31] = sup_at(xyz, pf, b, lane & 31, pc);
      if ((lane & 31) == 0) cval[myslot] = myv;
    }
    __syncthreads();
    // ---- select winner among the 16 LDS-resident candidates ----
    unsigned long long vwin = cval[0]; int wblk = 0;
#pragma unroll
    for (int w = 1; w < NBLK; ++w)
      if (cval[w] > vwin) { vwin = cval[w]; wblk = w; }
    if (tid < 32) cf[tid] = cand[wblk][tid];
    if (sb == 0 && tid == 0)
      cidx[b * Mc + it + 1] = (int)(~(unsigned int)(vwin & 0xffffffffu)) & (Npts - 1);
    __syncthreads();
  }
}

// ---- K2 (runs last): new_xyz output, f32 ----
__global__ __launch_bounds__(256) void gather_kernel(
    const float* __restrict__ xyz, const int* __restrict__ cidx,
    float* __restrict__ oxyz, int out_size) {
  int idx = blockIdx.x * 256 + threadIdx.x;   // B*3*M = 12288
  if (idx >= out_size || idx >= 12288) return;
  int m = idx & (Mc - 1);
  int t = idx >> 10;          // b*3 + c
  int b = t / 3;
  int ci = cidx[b * Mc + m] & (Npts - 1);
  oxyz[idx] = sanf(xyz[(size_t)t * Npts + ci], 888.0f);
}

// ---- K3: ball grouping, both radii in one pass; u16 index lists ----
__global__ __launch_bounds__(256) void ball_kernel(
    const float* __restrict__ xyz, const float* __restrict__ pf,
    const int* __restrict__ cidx,
    unsigned short* __restrict__ idx0, int* __restrict__ cnt0,
    unsigned short* __restrict__ idx1, int* __restrict__ cnt1) {
  const int b = blockIdx.x >> 6;
  const int mt = blockIdx.x & 63;
  const int tid = threadIdx.x;
  __shared__ float cf[16][32];
  __shared__ float csq[16];
  __shared__ unsigned int ent[16][128];
  __shared__ int lcnt[16];
  for (int i = tid; i < 16 * 32; i += 256) {
    int ml = i >> 5, c = i & 31;
    int ci = cidx[b * Mc + mt * 16 + ml] & (Npts - 1);
    cf[ml][c] = sup_at(xyz, pf, b, c, ci);
  }
  if (tid < 16) lcnt[tid] = 0;
  __syncthreads();
  if (tid < 16) {
    float a = 0.f;
#pragma unroll
    for (int c = 0; c < 32; ++c) a = fmaf(cf[tid][c], cf[tid][c], a);
    csq[tid] = a;
  }
  __syncthreads();
  for (int ch = 0; ch < Npts / 256; ++ch) {
    int p = ch * 256 + tid;
    float x[32];
#pragma unroll
    for (int c = 0; c < 32; ++c) x[c] = sup_at(xyz, pf, b, c, p);
    float sp = 0.f;
#pragma unroll
    for (int c = 0; c < 32; ++c) sp = fmaf(x[c], x[c], sp);
#pragma unroll 4
    for (int ml = 0; ml < 16; ++ml) {
      float dot = 0.f;
#pragma unroll
      for (int c = 0; c < 32; ++c) dot = fmaf(cf[ml][c], x[c], dot);
      float d = sp - 2.0f * dot + csq[ml];
      if (d <= 0.04f) {
        int pos = atomicAdd(&lcnt[ml], 1);
        if (pos < 128) ent[ml][pos] = (unsigned int)p | (d <= 0.01f ? 0x80000000u : 0u);
      }
    }
  }
  __syncthreads();
  if (tid < 16) {
    int ml = tid;
    int nn = lcnt[ml]; if (nn > 128) nn = 128;
    for (int i = 1; i < nn; ++i) {   // insertion sort by point index ascending
      unsigned int e = ent[ml][i]; unsigned int key = e & 0x7fffffffu;
      int j = i - 1;
      while (j >= 0 && (ent[ml][j] & 0x7fffffffu) > key) { ent[ml][j+1] = ent[ml][j]; --j; }
      ent[ml][j+1] = e;
    }
    int gm = b * Mc + mt * 16 + ml;
    int c1 = nn < 64 ? nn : 64;
    unsigned short first1 = nn > 0 ? (unsigned short)(ent[ml][0] & 0x7fffffffu) : 0;
    unsigned short* o1 = idx1 + (size_t)gm * 64;
    for (int j = 0; j < 64; ++j)
      o1[j] = j < c1 ? (unsigned short)(ent[ml][j] & 0x7fffffffu) : first1;
    cnt1[gm] = c1;
    unsigned short* o0 = idx0 + (size_t)gm * 32;
    int c0 = 0; unsigned short first0 = 0;
    for (int i = 0; i < nn && c0 < 32; ++i) {
      if (ent[ml][i] & 0x80000000u) {
        unsigned short nv = (unsigned short)(ent[ml][i] & 0x7fffffffu);
        if (c0 == 0) first0 = nv;
        o0[c0++] = nv;
      }
    }
    for (int j = c0; j < 32; ++j) o0[j] = first0;
    cnt0[gm] = c0;
  }
}

// ---- K4: attention, one wave per centroid. o = Wv @ (sum_j softmax_j * y_j). ----
template <int K>
__global__ __launch_bounds__(256) void attn_kernel(
    const float* __restrict__ xyz, const float* __restrict__ pf,
    const int* __restrict__ cidx,
    const unsigned short* __restrict__ idxS, const int* __restrict__ cntS,
    const float* __restrict__ wq, const float* __restrict__ wk,
    const float* __restrict__ wv, const float* __restrict__ wo,
    __hip_bfloat16* __restrict__ outA) {
  __shared__ float WqL[64*33], WkL[64*33], WvL[64*33], WoL[32*65];  // +1 pad rows
  __shared__ float xv[4][32];
  __shared__ float qv[4][64];
  __shared__ float yb[4][2][32];
  __shared__ float ov[4][64];
  __shared__ int cns[4];
  const int tid = threadIdx.x;
  const int wid = tid >> 6, lane = tid & 63;
  const int gid = blockIdx.x;
  const int b = gid >> 8;
  const int m = ((gid & 255) << 2) + wid;
  for (int i = tid; i < 2048; i += 256) {
    int r = i >> 5, c = i & 31;
    WqL[r*33 + c] = wq[i];
    WkL[r*33 + c] = wk[i];
    WvL[r*33 + c] = wv[i];
    int ro = i >> 6, co = i & 63;
    WoL[ro*65 + co] = wo[i];
  }
  if (lane < 32) {
    int ci = cidx[b * Mc + m] & (Npts - 1);
    xv[wid][lane] = sup_at(xyz, pf, b, lane, ci);
  }
  if (lane == 0) cns[wid] = cntS[b * Mc + m];
  __syncthreads();
  {
    float acc = 0.f;
#pragma unroll
    for (int c = 0; c < 32; ++c) acc = fmaf(WqL[lane*33 + c], xv[wid][c], acc);
    qv[wid][lane] = acc;
  }
  __syncthreads();
  int cnt = cns[wid];
  cnt = cnt < 1 ? 1 : (cnt > K ? K : cnt);
  const int jj = lane < K ? lane : 0;
  int nj = (int)idxS[((size_t)b*Mc + m)*K + jj] & (Npts - 1);
  float y[32];
#pragma unroll
  for (int c = 0; c < 32; ++c)
    y[c] = sup_at(xyz, pf, b, c, nj) - xv[wid][c];
  float w0 = 0.f, w1 = 0.f;
#pragma unroll 2
  for (int r = 0; r < 32; ++r) {
    float k0 = 0.f, k1 = 0.f;
#pragma unroll
    for (int c = 0; c < 32; ++c) {
      k0 = fmaf(WkL[r*33 + c], y[c], k0);
      k1 = fmaf(WkL[(r+32)*33 + c], y[c], k1);
    }
    w0 = fmaf(qv[wid][r], k0, w0);
    w1 = fmaf(qv[wid][r+32], k1, w1);
  }
  const float iscale = 0.17677669529663689f;  // 1/sqrt(32)
  w0 *= iscale; w1 *= iscale;
  if (lane >= cnt) { w0 = -1e9f; w1 = -1e9f; }
  float mx0 = w0, mx1 = w1;
#pragma unroll
  for (int d = K/2; d; d >>= 1) {
    mx0 = fmaxf(mx0, __shfl_xor(mx0, d, K));
    mx1 = fmaxf(mx1, __shfl_xor(mx1, d, K));
  }
  float e0 = __expf(w0 - mx0), e1 = __expf(w1 - mx1);
  float s0 = e0, s1 = e1;
#pragma unroll
  for (int d = K/2; d; d >>= 1) {
    s0 += __shfl_xor(s0, d, K);
    s1 += __shfl_xor(s1, d, K);
  }
  float wn0 = e0 / s0, wn1 = e1 / s1;
#pragma unroll
  for (int c = 0; c < 32; ++c) {
    float t0 = wn0 * y[c], t1 = wn1 * y[c];
#pragma unroll
    for (int d = K/2; d; d >>= 1) {
      t0 += __shfl_xor(t0, d, K);
      t1 += __shfl_xor(t1, d, K);
    }
    if (lane == 0) { yb[wid][0][c] = t0; yb[wid][1][c] = t1; }
  }
  __syncthreads();
  {
    const int h = lane >> 5;
    float a2 = 0.f;
#pragma unroll
    for (int c = 0; c < 32; ++c) a2 = fmaf(WvL[lane*33 + c], yb[wid][h][c], a2);
    ov[wid][lane] = a2;
  }
  __syncthreads();
  if (lane < 32) {
    float a3 = 0.f;
#pragma unroll
    for (int r = 0; r < 64; ++r) a3 = fmaf(WoL[lane*65 + r], ov[wid][r], a3);
    outA[((size_t)b*32 + lane)*Mc + m] = __float2bfloat16(a3 + xv[wid][lane]);
  }
}

// ---- K5: conv0 (64x32) + bias, BN stats via atomics ----
__global__ __launch_bounds__(256) void conv0_kernel(
    const __hip_bfloat16* __restrict__ inA, const float* __restrict__ w0,
    const float* __restrict__ b0, __hip_bfloat16* __restrict__ z0,
    float* __restrict__ ssum, float* __restrict__ ssq) {
  int idx = blockIdx.x * 256 + threadIdx.x;   // B*64*M
  int m = idx & (Mc - 1);
  int r = (idx >> 10) & 63;
  int b = idx >> 16;
  float acc = b0[r];
#pragma unroll
  for (int c = 0; c < 32; ++c)
    acc = fmaf(w0[r*32 + c], __bfloat162float(inA[((size_t)b*32 + c)*Mc + m]), acc);
  z0[((size_t)b*64 + r)*Mc + m] = __float2bfloat16(acc);
  float s = acc, q = acc * acc;
#pragma unroll
  for (int d = 32; d; d >>= 1) { s += __shfl_down(s, d, 64); q += __shfl_down(q, d, 64); }
  if ((threadIdx.x & 63) == 0) { atomicAdd(&ssum[r], s); atomicAdd(&ssq[r], q); }
}

// ---- K6: conv1 stats pass (folds bnfin0); optionally stores z1 f32 ----
__global__ __launch_bounds__(256) void conv1_stats_kernel(
    const __hip_bfloat16* __restrict__ z0,
    const float* __restrict__ ssum0, const float* __restrict__ ssq0,
    const float* __restrict__ g0, const float* __restrict__ t0,
    const float* __restrict__ w1, const float* __restrict__ b1,
    float* __restrict__ z1,                       // may be null
    float* __restrict__ ssum1, float* __restrict__ ssq1) {
  __shared__ float A0s[64], B0s[64];
  int tid = threadIdx.x;
  if (tid < 64) {
    float mu = ssum0[tid] * (1.0f/4096.0f);
    float var = ssq0[tid] * (1.0f/4096.0f) - mu * mu;
    if (var < 0.f) var = 0.f;
    float a = g0[tid] * rsqrtf(var + BN_EPS);
    A0s[tid] = a;
    B0s[tid] = t0[tid] - mu * a;
  }
  __syncthreads();
  int idx = blockIdx.x * 256 + tid;   // B*128*M
  int m = idx & (Mc - 1);
  int r2 = (idx >> 10) & 127;
  int b = idx >> 17;
  float acc = b1[r2];
#pragma unroll 8
  for (int r = 0; r < 64; ++r) {
    float u = fmaf(__bfloat162float(z0[((size_t)b*64 + r)*Mc + m]), A0s[r], B0s[r]);
    u = u > 0.f ? u : SLOPE * u;
    acc = fmaf(w1[r2*64 + r], u, acc);
  }
  if (z1) z1[idx] = acc;
  float s = acc, q = acc * acc;
#pragma unroll
  for (int d = 32; d; d >>= 1) { s += __shfl_down(s, d, 64); q += __shfl_down(q, d, 64); }
  if ((tid & 63) == 0) { atomicAdd(&ssum1[r2], s); atomicAdd(&ssq1[r2], q); }
}

// ---- K7: conv1 write pass (folds bnfin0+bnfin1); z1 path or recompute ----
__global__ __launch_bounds__(256) void conv1_write_kernel(
    const __hip_bfloat16* __restrict__ z0, const float* __restrict__ z1,
    const float* __restrict__ ssum0, const float* __restrict__ ssq0,
    const float* __restrict__ g0, const float* __restrict__ t0,
    const float* __restrict__ w1, const float* __restrict__ b1,
    const float* __restrict__ ssum1, const float* __restrict__ ssq1,
    const float* __restrict__ g1, const float* __restrict__ t1,
    float* __restrict__ outAll, int chOff, int out_size) {
  __shared__ float A0s[64], B0s[64];
  __shared__ float ab1[2];
  int tid = threadIdx.x;
  int idx = blockIdx.x * 256 + tid;   // B*128*M
  int m = idx & (Mc - 1);
  int r2 = (idx >> 10) & 127;         // uniform within block (256 | 1024)
  int b = idx >> 17;
  if (!z1 && tid < 64) {
    float mu = ssum0[tid] * (1.0f/4096.0f);
    float var = ssq0[tid] * (1.0f/4096.0f) - mu * mu;
    if (var < 0.f) var = 0.f;
    float a = g0[tid] * rsqrtf(var + BN_EPS);
    A0s[tid] = a;
    B0s[tid] = t0[tid] - mu * a;
  }
  if (tid == 0) {
    float mu = ssum1[r2] * (1.0f/4096.0f);
    float var = ssq1[r2] * (1.0f/4096.0f) - mu * mu;
    if (var < 0.f) var = 0.f;
    float a = g1[r2] * rsqrtf(var + BN_EPS);
    ab1[0] = a;
    ab1[1] = t1[r2] - mu * a;
  }
  __syncthreads();
  float acc;
  if (z1) {
    acc = z1[idx];
  } else {
    acc = b1[r2];
#pragma unroll 8
    for (int r = 0; r < 64; ++r) {
      float u = fmaf(__bfloat162float(z0[((size_t)b*64 + r)*Mc + m]), A0s[r], B0s[r]);
      u = u > 0.f ? u : SLOPE * u;
      acc = fmaf(w1[r2*64 + r], u, acc);
    }
  }
  float v = fmaf(acc, ab1[0], ab1[1]);
  size_t oidx = 12288 + ((size_t)b*256 + chOff + r2)*Mc + m;
  if (oidx < (size_t)out_size) outAll[oidx] = sanf(v, 777.0f);
}

extern "C" void kernel_launch(void* const* d_in, const int* in_sizes, int n_in,
                              void* d_out, int out_size, void* d_ws, size_t ws_size,
                              hipStream_t stream) {
  float* outb = (float*)d_out;
  int fillBlocks = (out_size + 255) / 256;
  if (n_in != 26 || in_sizes[0] != Bb*3*Npts || in_sizes[1] != Bb*29*Npts
      || in_sizes[2] != 2048) {
    fill_kernel<<<fillBlocks, 256, 0, stream>>>(outb, out_size, 7777.0f);
    return;
  }
  if (out_size != OUT_EXPECT) {
    fill_kernel<<<fillBlocks, 256, 0, stream>>>(outb, out_size, 23456.0f);
    return;
  }
  if (ws_size < WS_REQUIRED) {
    fill_kernel<<<fillBlocks, 256, 0, stream>>>(outb, out_size, 12345.0f);
    return;
  }
  const float* xyz = (const float*)d_in[0];
  const float* pf  = (const float*)d_in[1];
  char* ws = (char*)d_ws;
  int* cidx = (int*)(ws + OFF_CIDX);
  unsigned short* idx0 = (unsigned short*)(ws + OFF_IDX0);
  int* cnt0 = (int*)(ws + OFF_CNT0);
  unsigned short* idx1 = (unsigned short*)(ws + OFF_IDX1);
  int* cnt1 = (int*)(ws + OFF_CNT1);
  unsigned long long* fslots = (unsigned long long*)(ws + OFF_FSLOT);
  __hip_bfloat16* attn = (__hip_bfloat16*)(ws + OFF_ATTN);
  __hip_bfloat16* z0 = (__hip_bfloat16*)(ws + OFF_Z0);
  float* z1 = (ws_size >= WS_Z1_REQUIRED) ? (float*)(ws + OFF_Z1) : nullptr;

  hipMemsetAsync(ws, 0, ZERO_BYTES, stream);                 // stats etc
  hipMemsetAsync(ws + OFF_FSLOT, 0, FSLOT_BYTES, stream);    // fps val slots
  fps_kernel<<<Bb*NBLK, 512, 0, stream>>>(xyz, pf, cidx, fslots);
  ball_kernel<<<Bb*64, 256, 0, stream>>>(xyz, pf, cidx, idx0, cnt0, idx1, cnt1);

  for (int s = 0; s < 2; ++s) {
    const float* aq = (const float*)d_in[2 + s*12 + 0];
    const float* ak = (const float*)d_in[2 + s*12 + 1];
    const float* av = (const float*)d_in[2 + s*12 + 2];
    const float* ao = (const float*)d_in[2 + s*12 + 3];
    const float* w0 = (const float*)d_in[2 + s*12 + 4];
    const float* b0 = (const float*)d_in[2 + s*12 + 5];
    const float* g0 = (const float*)d_in[2 + s*12 + 6];
    const float* t0 = (const float*)d_in[2 + s*12 + 7];
    const float* w1 = (const float*)d_in[2 + s*12 + 8];
    const float* b1 = (const float*)d_in[2 + s*12 + 9];
    const float* g1 = (const float*)d_in[2 + s*12 + 10];
    const float* t1 = (const float*)d_in[2 + s*12 + 11];
    float* st = (float*)(ws + OFF_STATS) + (size_t)s*384;
    float *sum0 = st, *sq0 = st + 64, *sum1 = st + 128, *sq1 = st + 256;
    if (s == 0)
      attn_kernel<32><<<Bb*Mc/4, 256, 0, stream>>>(xyz, pf, cidx, idx0, cnt0, aq, ak, av, ao, attn);
    else
      attn_kernel<64><<<Bb*Mc/4, 256, 0, stream>>>(xyz, pf, cidx, idx1, cnt1, aq, ak, av, ao, attn);
    conv0_kernel<<<Bb*64*Mc/256, 256, 0, stream>>>(attn, w0, b0, z0, sum0, sq0);
    conv1_stats_kernel<<<Bb*128*Mc/256, 256, 0, stream>>>(z0, sum0, sq0, g0, t0,
                                                          w1, b1, z1, sum1, sq1);
    conv1_write_kernel<<<Bb*128*Mc/256, 256, 0, stream>>>(z0, z1, sum0, sq0, g0, t0,
                                                          w1, b1, sum1, sq1, g1, t1,
                                                          outb, s*128, out_size);
  }
  gather_kernel<<<48, 256, 0, stream>>>(xyz, cidx, outb, out_size);
}

// Round 13
// 2943.089 us; speedup vs baseline: 1.2235x; 1.2235x over previous
//
#include <hip/hip_runtime.h>
#include <hip/hip_bf16.h>

// PointNetMSG on MI355X. Inputs FP32, output FP32. Internal fp32, ws bf16.
// B=4, N=16384, Cs=32, M=1024, scales: (r=0.1,k=32),(r=0.2,k=64).
// R13: fps = R11 (proven 2163us) with ONE change — slot array transposed to
// [sb][it] so the 16 per-iteration publishes hit 16 different LLC lines
// (R11's [it][sb] packed them into one 128B line, serializing the 16
// atomicMax at that line's atomic unit; detection waits for the LAST one).
// Tail = R12's (conv1 bnfin folded, optional z1 f32 path) — measured 572us.

static constexpr int Bb = 4;
static constexpr int Npts = 16384;
static constexpr int Mc = 1024;
static constexpr int NBLK = 16;                      // fps blocks per batch
static constexpr int OUT_EXPECT = 12288 + 1048576;   // new_xyz + feats
#define BN_EPS 1e-5f
#define SLOPE 0.02f
#define SCOPE_AGT __HIP_MEMORY_SCOPE_AGENT

// ---- workspace layout (base 1,687,552 B proven; z1 path needs 3,784,704) ----
static constexpr size_t OFF_STATS = 33024;    // f32 [2][384]
static constexpr size_t ZERO_BYTES = 65536;
static constexpr size_t OFF_CIDX  = 65536;    // i32 [4][1024]
static constexpr size_t OFF_IDX0  = 81920;    // u16 [4][1024][32]
static constexpr size_t OFF_CNT0  = 344064;   // i32 [4][1024]
static constexpr size_t OFF_IDX1  = 360448;   // u16 [4][1024][64]
static constexpr size_t OFF_CNT1  = 884736;   // i32 [4][1024]
static constexpr size_t OFF_ATTN  = 901120;   // bf16 [4][32][1024]
static constexpr size_t OFF_Z0    = 1163264;  // bf16 [4][64][1024]
static constexpr size_t WS_REQUIRED = 1687552;
// fps val slots u64[4][16][1024] = 524288 B, aliased over attn/z0 (fps-only lifetime)
static constexpr size_t OFF_FSLOT = 901120;
static constexpr size_t FSLOT_BYTES = (size_t)Bb * Mc * NBLK * 8;
// optional z1 f32 [4][128][1024] = 2 MB beyond base layout (runtime-gated)
static constexpr size_t OFF_Z1 = 1687552;
static constexpr size_t WS_Z1_REQUIRED = OFF_Z1 + (size_t)Bb * 128 * Mc * 4;

__device__ __forceinline__ float sup_at(const float* xyz, const float* pf,
                                        int b, int c, int n) {
  return (c < 3) ? xyz[((size_t)b*3 + c)*Npts + n]
                 : pf[((size_t)b*29 + (c-3))*Npts + n];
}

__device__ __forceinline__ float sanf(float v, float repl) {
  if (!(v == v) || fabsf(v) > 1e30f) v = repl;
  return v;
}

__global__ __launch_bounds__(256) void fill_kernel(float* out, int n, float val) {
  int i = blockIdx.x * 256 + threadIdx.x;
  if (i < n) out[i] = val;
}

// ---- K1: FPS v8 (= R11 + transposed slots). 16 blocks x 512 thr per batch.
// Distance arithmetic bit-identical to R6-R12 (sequential __fadd_rn chain).
__global__ __launch_bounds__(512, 2) void fps_kernel(
    const float* __restrict__ xyz, const float* __restrict__ pf,
    int* __restrict__ cidx, unsigned long long* __restrict__ slots) {
  const int blk = blockIdx.x;
  const int b = blk >> 4;
  const int sb = blk & (NBLK - 1);
  const int tid = threadIdx.x;
  const int lane = tid & 63, wid = tid >> 6;
  float f0[32], f1[32];
  const int p0 = sb * 1024 + tid;
  const int p1 = p0 + 512;
  float d0 = 1e10f, d1 = 1e10f;
#pragma unroll
  for (int c = 0; c < 32; ++c) {
    f0[c] = sup_at(xyz, pf, b, c, p0);
    f1[c] = sup_at(xyz, pf, b, c, p1);
  }
  __shared__ float cf[32];
  __shared__ unsigned long long red[8];
  if (sb == 0 && tid == 0) cidx[b * Mc] = 0;
  if (tid < 32) cf[tid] = sup_at(xyz, pf, b, tid, 0);   // centroid 0 = point 0
  __syncthreads();
  unsigned long long* slotb = slots + (size_t)b * Mc * NBLK;   // [sb][it] layout
  for (int it = 0; it < Mc - 1; ++it) {
    // ---- local distance update (exact R6 arithmetic) ----
    float cc[32];
#pragma unroll
    for (int c = 0; c < 32; ++c) cc[c] = cf[c];
    {
      float d = 0.f, e = 0.f;
#pragma unroll
      for (int c = 0; c < 32; ++c) {
        float t0 = f0[c] - cc[c];
        float s0 = __fmul_rn(t0, t0);
        d = (c == 0) ? s0 : __fadd_rn(d, s0);
        float t1 = f1[c] - cc[c];
        float s1 = __fmul_rn(t1, t1);
        e = (c == 0) ? s1 : __fadd_rn(e, s1);
      }
      d0 = fminf(d0, d);
      d1 = fminf(d1, e);
    }
    float bd; int bp;
    if (d0 >= d1) { bd = d0; bp = p0; } else { bd = d1; bp = p1; }  // p0<p1: first-index tiebreak
    unsigned long long v =
        ((unsigned long long)__float_as_uint(bd) << 32) | (unsigned int)(~(unsigned int)bp);
#pragma unroll
    for (int d = 32; d; d >>= 1) {
      unsigned long long o = __shfl_xor(v, d, 64);
      if (o > v) v = o;
    }
    if (lane == 0) red[wid] = v;
    __syncthreads();
    if (tid == 0) {
      unsigned long long vb = red[0];
#pragma unroll
      for (int w = 1; w < 8; ++w) if (red[w] > vb) vb = red[w];
      atomicMax(&slotb[(size_t)sb * Mc + it], vb);   // own line: parallel across blocks
    }
    // ---- wave 0: poll 16 slots (16 distinct lines, concurrent LLC reads) ----
    if (wid == 0) {
      unsigned long long myv = 0;
      if (lane < NBLK) {
        const unsigned long long* sp = &slotb[(size_t)lane * Mc + it];
        while ((myv = __hip_atomic_load(sp, __ATOMIC_RELAXED, SCOPE_AGT)) == 0ull)
          __builtin_amdgcn_s_sleep(1);
      }
      unsigned long long mv = myv;
#pragma unroll
      for (int d = 8; d; d >>= 1) {
        unsigned long long o = __shfl_xor(mv, d, 16);
        if (o > mv) mv = o;
      }
      unsigned long long vwin = __shfl(mv, 0, 64);
      int idxWin = (int)(~(unsigned int)(vwin & 0xffffffffu)) & (Npts - 1);
      if (lane < 32) cf[lane] = sup_at(xyz, pf, b, lane, idxWin);  // winner-only gather
      if (lane == 0 && sb == 0) cidx[b * Mc + it + 1] = idxWin;
    }
    __syncthreads();
  }
}

// ---- K2 (runs last): new_xyz output, f32 ----
__global__ __launch_bounds__(256) void gather_kernel(
    const float* __restrict__ xyz, const int* __restrict__ cidx,
    float* __restrict__ oxyz, int out_size) {
  int idx = blockIdx.x * 256 + threadIdx.x;   // B*3*M = 12288
  if (idx >= out_size || idx >= 12288) return;
  int m = idx & (Mc - 1);
  int t = idx >> 10;          // b*3 + c
  int b = t / 3;
  int ci = cidx[b * Mc + m] & (Npts - 1);
  oxyz[idx] = sanf(xyz[(size_t)t * Npts + ci], 888.0f);
}

// ---- K3: ball grouping, both radii in one pass; u16 index lists ----
__global__ __launch_bounds__(256) void ball_kernel(
    const float* __restrict__ xyz, const float* __restrict__ pf,
    const int* __restrict__ cidx,
    unsigned short* __restrict__ idx0, int* __restrict__ cnt0,
    unsigned short* __restrict__ idx1, int* __restrict__ cnt1) {
  const int b = blockIdx.x >> 6;
  const int mt = blockIdx.x & 63;
  const int tid = threadIdx.x;
  __shared__ float cf[16][32];
  __shared__ float csq[16];
  __shared__ unsigned int ent[16][128];
  __shared__ int lcnt[16];
  for (int i = tid; i < 16 * 32; i += 256) {
    int ml = i >> 5, c = i & 31;
    int ci = cidx[b * Mc + mt * 16 + ml] & (Npts - 1);
    cf[ml][c] = sup_at(xyz, pf, b, c, ci);
  }
  if (tid < 16) lcnt[tid] = 0;
  __syncthreads();
  if (tid < 16) {
    float a = 0.f;
#pragma unroll
    for (int c = 0; c < 32; ++c) a = fmaf(cf[tid][c], cf[tid][c], a);
    csq[tid] = a;
  }
  __syncthreads();
  for (int ch = 0; ch < Npts / 256; ++ch) {
    int p = ch * 256 + tid;
    float x[32];
#pragma unroll
    for (int c = 0; c < 32; ++c) x[c] = sup_at(xyz, pf, b, c, p);
    float sp = 0.f;
#pragma unroll
    for (int c = 0; c < 32; ++c) sp = fmaf(x[c], x[c], sp);
#pragma unroll 4
    for (int ml = 0; ml < 16; ++ml) {
      float dot = 0.f;
#pragma unroll
      for (int c = 0; c < 32; ++c) dot = fmaf(cf[ml][c], x[c], dot);
      float d = sp - 2.0f * dot + csq[ml];
      if (d <= 0.04f) {
        int pos = atomicAdd(&lcnt[ml], 1);
        if (pos < 128) ent[ml][pos] = (unsigned int)p | (d <= 0.01f ? 0x80000000u : 0u);
      }
    }
  }
  __syncthreads();
  if (tid < 16) {
    int ml = tid;
    int nn = lcnt[ml]; if (nn > 128) nn = 128;
    for (int i = 1; i < nn; ++i) {   // insertion sort by point index ascending
      unsigned int e = ent[ml][i]; unsigned int key = e & 0x7fffffffu;
      int j = i - 1;
      while (j >= 0 && (ent[ml][j] & 0x7fffffffu) > key) { ent[ml][j+1] = ent[ml][j]; --j; }
      ent[ml][j+1] = e;
    }
    int gm = b * Mc + mt * 16 + ml;
    int c1 = nn < 64 ? nn : 64;
    unsigned short first1 = nn > 0 ? (unsigned short)(ent[ml][0] & 0x7fffffffu) : 0;
    unsigned short* o1 = idx1 + (size_t)gm * 64;
    for (int j = 0; j < 64; ++j)
      o1[j] = j < c1 ? (unsigned short)(ent[ml][j] & 0x7fffffffu) : first1;
    cnt1[gm] = c1;
    unsigned short* o0 = idx0 + (size_t)gm * 32;
    int c0 = 0; unsigned short first0 = 0;
    for (int i = 0; i < nn && c0 < 32; ++i) {
      if (ent[ml][i] & 0x80000000u) {
        unsigned short nv = (unsigned short)(ent[ml][i] & 0x7fffffffu);
        if (c0 == 0) first0 = nv;
        o0[c0++] = nv;
      }
    }
    for (int j = c0; j < 32; ++j) o0[j] = first0;
    cnt0[gm] = c0;
  }
}

// ---- K4: attention, one wave per centroid. o = Wv @ (sum_j softmax_j * y_j). ----
template <int K>
__global__ __launch_bounds__(256) void attn_kernel(
    const float* __restrict__ xyz, const float* __restrict__ pf,
    const int* __restrict__ cidx,
    const unsigned short* __restrict__ idxS, const int* __restrict__ cntS,
    const float* __restrict__ wq, const float* __restrict__ wk,
    const float* __restrict__ wv, const float* __restrict__ wo,
    __hip_bfloat16* __restrict__ outA) {
  __shared__ float WqL[64*33], WkL[64*33], WvL[64*33], WoL[32*65];  // +1 pad rows
  __shared__ float xv[4][32];
  __shared__ float qv[4][64];
  __shared__ float yb[4][2][32];
  __shared__ float ov[4][64];
  __shared__ int cns[4];
  const int tid = threadIdx.x;
  const int wid = tid >> 6, lane = tid & 63;
  const int gid = blockIdx.x;
  const int b = gid >> 8;
  const int m = ((gid & 255) << 2) + wid;
  for (int i = tid; i < 2048; i += 256) {
    int r = i >> 5, c = i & 31;
    WqL[r*33 + c] = wq[i];
    WkL[r*33 + c] = wk[i];
    WvL[r*33 + c] = wv[i];
    int ro = i >> 6, co = i & 63;
    WoL[ro*65 + co] = wo[i];
  }
  if (lane < 32) {
    int ci = cidx[b * Mc + m] & (Npts - 1);
    xv[wid][lane] = sup_at(xyz, pf, b, lane, ci);
  }
  if (lane == 0) cns[wid] = cntS[b * Mc + m];
  __syncthreads();
  {
    float acc = 0.f;
#pragma unroll
    for (int c = 0; c < 32; ++c) acc = fmaf(WqL[lane*33 + c], xv[wid][c], acc);
    qv[wid][lane] = acc;
  }
  __syncthreads();
  int cnt = cns[wid];
  cnt = cnt < 1 ? 1 : (cnt > K ? K : cnt);
  const int jj = lane < K ? lane : 0;
  int nj = (int)idxS[((size_t)b*Mc + m)*K + jj] & (Npts - 1);
  float y[32];
#pragma unroll
  for (int c = 0; c < 32; ++c)
    y[c] = sup_at(xyz, pf, b, c, nj) - xv[wid][c];
  float w0 = 0.f, w1 = 0.f;
#pragma unroll 2
  for (int r = 0; r < 32; ++r) {
    float k0 = 0.f, k1 = 0.f;
#pragma unroll
    for (int c = 0; c < 32; ++c) {
      k0 = fmaf(WkL[r*33 + c], y[c], k0);
      k1 = fmaf(WkL[(r+32)*33 + c], y[c], k1);
    }
    w0 = fmaf(qv[wid][r], k0, w0);
    w1 = fmaf(qv[wid][r+32], k1, w1);
  }
  const float iscale = 0.17677669529663689f;  // 1/sqrt(32)
  w0 *= iscale; w1 *= iscale;
  if (lane >= cnt) { w0 = -1e9f; w1 = -1e9f; }
  float mx0 = w0, mx1 = w1;
#pragma unroll
  for (int d = K/2; d; d >>= 1) {
    mx0 = fmaxf(mx0, __shfl_xor(mx0, d, K));
    mx1 = fmaxf(mx1, __shfl_xor(mx1, d, K));
  }
  float e0 = __expf(w0 - mx0), e1 = __expf(w1 - mx1);
  float s0 = e0, s1 = e1;
#pragma unroll
  for (int d = K/2; d; d >>= 1) {
    s0 += __shfl_xor(s0, d, K);
    s1 += __shfl_xor(s1, d, K);
  }
  float wn0 = e0 / s0, wn1 = e1 / s1;
#pragma unroll
  for (int c = 0; c < 32; ++c) {
    float t0 = wn0 * y[c], t1 = wn1 * y[c];
#pragma unroll
    for (int d = K/2; d; d >>= 1) {
      t0 += __shfl_xor(t0, d, K);
      t1 += __shfl_xor(t1, d, K);
    }
    if (lane == 0) { yb[wid][0][c] = t0; yb[wid][1][c] = t1; }
  }
  __syncthreads();
  {
    const int h = lane >> 5;
    float a2 = 0.f;
#pragma unroll
    for (int c = 0; c < 32; ++c) a2 = fmaf(WvL[lane*33 + c], yb[wid][h][c], a2);
    ov[wid][lane] = a2;
  }
  __syncthreads();
  if (lane < 32) {
    float a3 = 0.f;
#pragma unroll
    for (int r = 0; r < 64; ++r) a3 = fmaf(WoL[lane*65 + r], ov[wid][r], a3);
    outA[((size_t)b*32 + lane)*Mc + m] = __float2bfloat16(a3 + xv[wid][lane]);
  }
}

// ---- K5: conv0 (64x32) + bias, BN stats via atomics ----
__global__ __launch_bounds__(256) void conv0_kernel(
    const __hip_bfloat16* __restrict__ inA, const float* __restrict__ w0,
    const float* __restrict__ b0, __hip_bfloat16* __restrict__ z0,
    float* __restrict__ ssum, float* __restrict__ ssq) {
  int idx = blockIdx.x * 256 + threadIdx.x;   // B*64*M
  int m = idx & (Mc - 1);
  int r = (idx >> 10) & 63;
  int b = idx >> 16;
  float acc = b0[r];
#pragma unroll
  for (int c = 0; c < 32; ++c)
    acc = fmaf(w0[r*32 + c], __bfloat162float(inA[((size_t)b*32 + c)*Mc + m]), acc);
  z0[((size_t)b*64 + r)*Mc + m] = __float2bfloat16(acc);
  float s = acc, q = acc * acc;
#pragma unroll
  for (int d = 32; d; d >>= 1) { s += __shfl_down(s, d, 64); q += __shfl_down(q, d, 64); }
  if ((threadIdx.x & 63) == 0) { atomicAdd(&ssum[r], s); atomicAdd(&ssq[r], q); }
}

// ---- K6: conv1 stats pass (folds bnfin0); optionally stores z1 f32 ----
__global__ __launch_bounds__(256) void conv1_stats_kernel(
    const __hip_bfloat16* __restrict__ z0,
    const float* __restrict__ ssum0, const float* __restrict__ ssq0,
    const float* __restrict__ g0, const float* __restrict__ t0,
    const float* __restrict__ w1, const float* __restrict__ b1,
    float* __restrict__ z1,                       // may be null
    float* __restrict__ ssum1, float* __restrict__ ssq1) {
  __shared__ float A0s[64], B0s[64];
  int tid = threadIdx.x;
  if (tid < 64) {
    float mu = ssum0[tid] * (1.0f/4096.0f);
    float var = ssq0[tid] * (1.0f/4096.0f) - mu * mu;
    if (var < 0.f) var = 0.f;
    float a = g0[tid] * rsqrtf(var + BN_EPS);
    A0s[tid] = a;
    B0s[tid] = t0[tid] - mu * a;
  }
  __syncthreads();
  int idx = blockIdx.x * 256 + tid;   // B*128*M
  int m = idx & (Mc - 1);
  int r2 = (idx >> 10) & 127;
  int b = idx >> 17;
  float acc = b1[r2];
#pragma unroll 8
  for (int r = 0; r < 64; ++r) {
    float u = fmaf(__bfloat162float(z0[((size_t)b*64 + r)*Mc + m]), A0s[r], B0s[r]);
    u = u > 0.f ? u : SLOPE * u;
    acc = fmaf(w1[r2*64 + r], u, acc);
  }
  if (z1) z1[idx] = acc;
  float s = acc, q = acc * acc;
#pragma unroll
  for (int d = 32; d; d >>= 1) { s += __shfl_down(s, d, 64); q += __shfl_down(q, d, 64); }
  if ((tid & 63) == 0) { atomicAdd(&ssum1[r2], s); atomicAdd(&ssq1[r2], q); }
}

// ---- K7: conv1 write pass (folds bnfin0+bnfin1); z1 path or recompute ----
__global__ __launch_bounds__(256) void conv1_write_kernel(
    const __hip_bfloat16* __restrict__ z0, const float* __restrict__ z1,
    const float* __restrict__ ssum0, const float* __restrict__ ssq0,
    const float* __restrict__ g0, const float* __restrict__ t0,
    const float* __restrict__ w1, const float* __restrict__ b1,
    const float* __restrict__ ssum1, const float* __restrict__ ssq1,
    const float* __restrict__ g1, const float* __restrict__ t1,
    float* __restrict__ outAll, int chOff, int out_size) {
  __shared__ float A0s[64], B0s[64];
  __shared__ float ab1[2];
  int tid = threadIdx.x;
  int idx = blockIdx.x * 256 + tid;   // B*128*M
  int m = idx & (Mc - 1);
  int r2 = (idx >> 10) & 127;         // uniform within block (256 | 1024)
  int b = idx >> 17;
  if (!z1 && tid < 64) {
    float mu = ssum0[tid] * (1.0f/4096.0f);
    float var = ssq0[tid] * (1.0f/4096.0f) - mu * mu;
    if (var < 0.f) var = 0.f;
    float a = g0[tid] * rsqrtf(var + BN_EPS);
    A0s[tid] = a;
    B0s[tid] = t0[tid] - mu * a;
  }
  if (tid == 0) {
    float mu = ssum1[r2] * (1.0f/4096.0f);
    float var = ssq1[r2] * (1.0f/4096.0f) - mu * mu;
    if (var < 0.f) var = 0.f;
    float a = g1[r2] * rsqrtf(var + BN_EPS);
    ab1[0] = a;
    ab1[1] = t1[r2] - mu * a;
  }
  __syncthreads();
  float acc;
  if (z1) {
    acc = z1[idx];
  } else {
    acc = b1[r2];
#pragma unroll 8
    for (int r = 0; r < 64; ++r) {
      float u = fmaf(__bfloat162float(z0[((size_t)b*64 + r)*Mc + m]), A0s[r], B0s[r]);
      u = u > 0.f ? u : SLOPE * u;
      acc = fmaf(w1[r2*64 + r], u, acc);
    }
  }
  float v = fmaf(acc, ab1[0], ab1[1]);
  size_t oidx = 12288 + ((size_t)b*256 + chOff + r2)*Mc + m;
  if (oidx < (size_t)out_size) outAll[oidx] = sanf(v, 777.0f);
}

extern "C" void kernel_launch(void* const* d_in, const int* in_sizes, int n_in,
                              void* d_out, int out_size, void* d_ws, size_t ws_size,
                              hipStream_t stream) {
  float* outb = (float*)d_out;
  int fillBlocks = (out_size + 255) / 256;
  if (n_in != 26 || in_sizes[0] != Bb*3*Npts || in_sizes[1] != Bb*29*Npts
      || in_sizes[2] != 2048) {
    fill_kernel<<<fillBlocks, 256, 0, stream>>>(outb, out_size, 7777.0f);
    return;
  }
  if (out_size != OUT_EXPECT) {
    fill_kernel<<<fillBlocks, 256, 0, stream>>>(outb, out_size, 23456.0f);
    return;
  }
  if (ws_size < WS_REQUIRED) {
    fill_kernel<<<fillBlocks, 256, 0, stream>>>(outb, out_size, 12345.0f);
    return;
  }
  const float* xyz = (const float*)d_in[0];
  const float* pf  = (const float*)d_in[1];
  char* ws = (char*)d_ws;
  int* cidx = (int*)(ws + OFF_CIDX);
  unsigned short* idx0 = (unsigned short*)(ws + OFF_IDX0);
  int* cnt0 = (int*)(ws + OFF_CNT0);
  unsigned short* idx1 = (unsigned short*)(ws + OFF_IDX1);
  int* cnt1 = (int*)(ws + OFF_CNT1);
  unsigned long long* fslots = (unsigned long long*)(ws + OFF_FSLOT);
  __hip_bfloat16* attn = (__hip_bfloat16*)(ws + OFF_ATTN);
  __hip_bfloat16* z0 = (__hip_bfloat16*)(ws + OFF_Z0);
  float* z1 = (ws_size >= WS_Z1_REQUIRED) ? (float*)(ws + OFF_Z1) : nullptr;

  hipMemsetAsync(ws, 0, ZERO_BYTES, stream);                 // stats etc
  hipMemsetAsync(ws + OFF_FSLOT, 0, FSLOT_BYTES, stream);    // fps val slots
  fps_kernel<<<Bb*NBLK, 512, 0, stream>>>(xyz, pf, cidx, fslots);
  ball_kernel<<<Bb*64, 256, 0, stream>>>(xyz, pf, cidx, idx0, cnt0, idx1, cnt1);

  for (int s = 0; s < 2; ++s) {
    const float* aq = (const float*)d_in[2 + s*12 + 0];
    const float* ak = (const float*)d_in[2 + s*12 + 1];
    const float* av = (const float*)d_in[2 + s*12 + 2];
    const float* ao = (const float*)d_in[2 + s*12 + 3];
    const float* w0 = (const float*)d_in[2 + s*12 + 4];
    const float* b0 = (const float*)d_in[2 + s*12 + 5];
    const float* g0 = (const float*)d_in[2 + s*12 + 6];
    const float* t0 = (const float*)d_in[2 + s*12 + 7];
    const float* w1 = (const float*)d_in[2 + s*12 + 8];
    const float* b1 = (const float*)d_in[2 + s*12 + 9];
    const float* g1 = (const float*)d_in[2 + s*12 + 10];
    const float* t1 = (const float*)d_in[2 + s*12 + 11];
    float* st = (float*)(ws + OFF_STATS) + (size_t)s*384;
    float *sum0 = st, *sq0 = st + 64, *sum1 = st + 128, *sq1 = st + 256;
    if (s == 0)
      attn_kernel<32><<<Bb*Mc/4, 256, 0, stream>>>(xyz, pf, cidx, idx0, cnt0, aq, ak, av, ao, attn);
    else
      attn_kernel<64><<<Bb*Mc/4, 256, 0, stream>>>(xyz, pf, cidx, idx1, cnt1, aq, ak, av, ao, attn);
    conv0_kernel<<<Bb*64*Mc/256, 256, 0, stream>>>(attn, w0, b0, z0, sum0, sq0);
    conv1_stats_kernel<<<Bb*128*Mc/256, 256, 0, stream>>>(z0, sum0, sq0, g0, t0,
                                                          w1, b1, z1, sum1, sq1);
    conv1_write_kernel<<<Bb*128*Mc/256, 256, 0, stream>>>(z0, z1, sum0, sq0, g0, t0,
                                                          w1, b1, sum1, sq1, g1, t1,
                                                          outb, s*128, out_size);
  }
  gather_kernel<<<48, 256, 0, stream>>>(xyz, cidx, outb, out_size);
}

// Round 14
// 2739.022 us; speedup vs baseline: 1.3146x; 1.0745x over previous
//
#include <hip/hip_runtime.h>
#include <hip/hip_bf16.h>

// PointNetMSG on MI355X. Inputs FP32, output FP32. Internal fp32, ws bf16.
// B=4, N=16384, Cs=32, M=1024, scales: (r=0.1,k=32),(r=0.2,k=64).
// R14: consolidation. fps = R11 verbatim (measured 2163us; packed [it][sb]
// slots, atomicMax publish, 16-lane RELAXED-load poll + s_sleep, winner-only
// gather — R9/R10/R12/R13 all regressed vs it). Tail = R12/R13 (measured
// ~572us; bnfin folded into conv1, z1-f32 path active per WRITE_SIZE).

static constexpr int Bb = 4;
static constexpr int Npts = 16384;
static constexpr int Mc = 1024;
static constexpr int NBLK = 16;                      // fps blocks per batch
static constexpr int OUT_EXPECT = 12288 + 1048576;   // new_xyz + feats
#define BN_EPS 1e-5f
#define SLOPE 0.02f
#define SCOPE_AGT __HIP_MEMORY_SCOPE_AGENT

// ---- workspace layout (base 1,687,552 B proven; z1 path needs 3,784,704,
// active per R13 counters) ----
static constexpr size_t OFF_STATS = 33024;    // f32 [2][384]
static constexpr size_t ZERO_BYTES = 65536;
static constexpr size_t OFF_CIDX  = 65536;    // i32 [4][1024]
static constexpr size_t OFF_IDX0  = 81920;    // u16 [4][1024][32]
static constexpr size_t OFF_CNT0  = 344064;   // i32 [4][1024]
static constexpr size_t OFF_IDX1  = 360448;   // u16 [4][1024][64]
static constexpr size_t OFF_CNT1  = 884736;   // i32 [4][1024]
static constexpr size_t OFF_ATTN  = 901120;   // bf16 [4][32][1024]
static constexpr size_t OFF_Z0    = 1163264;  // bf16 [4][64][1024]
static constexpr size_t WS_REQUIRED = 1687552;
// fps val slots u64[4][1024][16] = 524288 B, aliased over attn/z0 (fps-only lifetime)
static constexpr size_t OFF_FSLOT = 901120;
static constexpr size_t FSLOT_BYTES = (size_t)Bb * Mc * NBLK * 8;
// optional z1 f32 [4][128][1024] = 2 MB beyond base layout (runtime-gated)
static constexpr size_t OFF_Z1 = 1687552;
static constexpr size_t WS_Z1_REQUIRED = OFF_Z1 + (size_t)Bb * 128 * Mc * 4;

__device__ __forceinline__ float sup_at(const float* xyz, const float* pf,
                                        int b, int c, int n) {
  return (c < 3) ? xyz[((size_t)b*3 + c)*Npts + n]
                 : pf[((size_t)b*29 + (c-3))*Npts + n];
}

__device__ __forceinline__ float sanf(float v, float repl) {
  if (!(v == v) || fabsf(v) > 1e30f) v = repl;
  return v;
}

__global__ __launch_bounds__(256) void fill_kernel(float* out, int n, float val) {
  int i = blockIdx.x * 256 + threadIdx.x;
  if (i < n) out[i] = val;
}

// ---- K1: FPS (R11 verbatim). 16 blocks x 512 threads per batch.
// Distance arithmetic bit-identical to R6-R13 (sequential __fadd_rn chain).
__global__ __launch_bounds__(512, 2) void fps_kernel(
    const float* __restrict__ xyz, const float* __restrict__ pf,
    int* __restrict__ cidx, unsigned long long* __restrict__ slots) {
  const int blk = blockIdx.x;
  const int b = blk >> 4;
  const int sb = blk & (NBLK - 1);
  const int tid = threadIdx.x;
  const int lane = tid & 63, wid = tid >> 6;
  float f0[32], f1[32];
  const int p0 = sb * 1024 + tid;
  const int p1 = p0 + 512;
  float d0 = 1e10f, d1 = 1e10f;
#pragma unroll
  for (int c = 0; c < 32; ++c) {
    f0[c] = sup_at(xyz, pf, b, c, p0);
    f1[c] = sup_at(xyz, pf, b, c, p1);
  }
  __shared__ float cf[32];
  __shared__ unsigned long long red[8];
  if (sb == 0 && tid == 0) cidx[b * Mc] = 0;
  if (tid < 32) cf[tid] = sup_at(xyz, pf, b, tid, 0);   // centroid 0 = point 0
  __syncthreads();
  unsigned long long* slotb = slots + (size_t)b * Mc * NBLK;   // [it][sb] packed layout
  for (int it = 0; it < Mc - 1; ++it) {
    // ---- local distance update (exact R6 arithmetic) ----
    float cc[32];
#pragma unroll
    for (int c = 0; c < 32; ++c) cc[c] = cf[c];
    {
      float d = 0.f, e = 0.f;
#pragma unroll
      for (int c = 0; c < 32; ++c) {
        float t0 = f0[c] - cc[c];
        float s0 = __fmul_rn(t0, t0);
        d = (c == 0) ? s0 : __fadd_rn(d, s0);
        float t1 = f1[c] - cc[c];
        float s1 = __fmul_rn(t1, t1);
        e = (c == 0) ? s1 : __fadd_rn(e, s1);
      }
      d0 = fminf(d0, d);
      d1 = fminf(d1, e);
    }
    float bd; int bp;
    if (d0 >= d1) { bd = d0; bp = p0; } else { bd = d1; bp = p1; }  // p0<p1: first-index tiebreak
    unsigned long long v =
        ((unsigned long long)__float_as_uint(bd) << 32) | (unsigned int)(~(unsigned int)bp);
#pragma unroll
    for (int d = 32; d; d >>= 1) {
      unsigned long long o = __shfl_xor(v, d, 64);
      if (o > v) v = o;
    }
    if (lane == 0) red[wid] = v;
    __syncthreads();
    if (tid == 0) {
      unsigned long long vb = red[0];
#pragma unroll
      for (int w = 1; w < 8; ++w) if (red[w] > vb) vb = red[w];
      atomicMax(&slotb[(size_t)it * NBLK + sb], vb);   // single publish, val != 0 always
    }
    // ---- wave 0: poll 16 val slots via concurrent LLC reads, pick winner ----
    if (wid == 0) {
      unsigned long long myv = 0;
      if (lane < NBLK) {
        const unsigned long long* sp = &slotb[(size_t)it * NBLK + lane];
        while ((myv = __hip_atomic_load(sp, __ATOMIC_RELAXED, SCOPE_AGT)) == 0ull)
          __builtin_amdgcn_s_sleep(1);
      }
      unsigned long long mv = myv;
#pragma unroll
      for (int d = 8; d; d >>= 1) {
        unsigned long long o = __shfl_xor(mv, d, 16);
        if (o > mv) mv = o;
      }
      unsigned long long vwin = __shfl(mv, 0, 64);
      int idxWin = (int)(~(unsigned int)(vwin & 0xffffffffu)) & (Npts - 1);
      if (lane < 32) cf[lane] = sup_at(xyz, pf, b, lane, idxWin);  // winner-only gather
      if (lane == 0 && sb == 0) cidx[b * Mc + it + 1] = idxWin;
    }
    __syncthreads();
  }
}

// ---- K2 (runs last): new_xyz output, f32 ----
__global__ __launch_bounds__(256) void gather_kernel(
    const float* __restrict__ xyz, const int* __restrict__ cidx,
    float* __restrict__ oxyz, int out_size) {
  int idx = blockIdx.x * 256 + threadIdx.x;   // B*3*M = 12288
  if (idx >= out_size || idx >= 12288) return;
  int m = idx & (Mc - 1);
  int t = idx >> 10;          // b*3 + c
  int b = t / 3;
  int ci = cidx[b * Mc + m] & (Npts - 1);
  oxyz[idx] = sanf(xyz[(size_t)t * Npts + ci], 888.0f);
}

// ---- K3: ball grouping, both radii in one pass; u16 index lists ----
__global__ __launch_bounds__(256) void ball_kernel(
    const float* __restrict__ xyz, const float* __restrict__ pf,
    const int* __restrict__ cidx,
    unsigned short* __restrict__ idx0, int* __restrict__ cnt0,
    unsigned short* __restrict__ idx1, int* __restrict__ cnt1) {
  const int b = blockIdx.x >> 6;
  const int mt = blockIdx.x & 63;
  const int tid = threadIdx.x;
  __shared__ float cf[16][32];
  __shared__ float csq[16];
  __shared__ unsigned int ent[16][128];
  __shared__ int lcnt[16];
  for (int i = tid; i < 16 * 32; i += 256) {
    int ml = i >> 5, c = i & 31;
    int ci = cidx[b * Mc + mt * 16 + ml] & (Npts - 1);
    cf[ml][c] = sup_at(xyz, pf, b, c, ci);
  }
  if (tid < 16) lcnt[tid] = 0;
  __syncthreads();
  if (tid < 16) {
    float a = 0.f;
#pragma unroll
    for (int c = 0; c < 32; ++c) a = fmaf(cf[tid][c], cf[tid][c], a);
    csq[tid] = a;
  }
  __syncthreads();
  for (int ch = 0; ch < Npts / 256; ++ch) {
    int p = ch * 256 + tid;
    float x[32];
#pragma unroll
    for (int c = 0; c < 32; ++c) x[c] = sup_at(xyz, pf, b, c, p);
    float sp = 0.f;
#pragma unroll
    for (int c = 0; c < 32; ++c) sp = fmaf(x[c], x[c], sp);
#pragma unroll 4
    for (int ml = 0; ml < 16; ++ml) {
      float dot = 0.f;
#pragma unroll
      for (int c = 0; c < 32; ++c) dot = fmaf(cf[ml][c], x[c], dot);
      float d = sp - 2.0f * dot + csq[ml];
      if (d <= 0.04f) {
        int pos = atomicAdd(&lcnt[ml], 1);
        if (pos < 128) ent[ml][pos] = (unsigned int)p | (d <= 0.01f ? 0x80000000u : 0u);
      }
    }
  }
  __syncthreads();
  if (tid < 16) {
    int ml = tid;
    int nn = lcnt[ml]; if (nn > 128) nn = 128;
    for (int i = 1; i < nn; ++i) {   // insertion sort by point index ascending
      unsigned int e = ent[ml][i]; unsigned int key = e & 0x7fffffffu;
      int j = i - 1;
      while (j >= 0 && (ent[ml][j] & 0x7fffffffu) > key) { ent[ml][j+1] = ent[ml][j]; --j; }
      ent[ml][j+1] = e;
    }
    int gm = b * Mc + mt * 16 + ml;
    int c1 = nn < 64 ? nn : 64;
    unsigned short first1 = nn > 0 ? (unsigned short)(ent[ml][0] & 0x7fffffffu) : 0;
    unsigned short* o1 = idx1 + (size_t)gm * 64;
    for (int j = 0; j < 64; ++j)
      o1[j] = j < c1 ? (unsigned short)(ent[ml][j] & 0x7fffffffu) : first1;
    cnt1[gm] = c1;
    unsigned short* o0 = idx0 + (size_t)gm * 32;
    int c0 = 0; unsigned short first0 = 0;
    for (int i = 0; i < nn && c0 < 32; ++i) {
      if (ent[ml][i] & 0x80000000u) {
        unsigned short nv = (unsigned short)(ent[ml][i] & 0x7fffffffu);
        if (c0 == 0) first0 = nv;
        o0[c0++] = nv;
      }
    }
    for (int j = c0; j < 32; ++j) o0[j] = first0;
    cnt0[gm] = c0;
  }
}

// ---- K4: attention, one wave per centroid. o = Wv @ (sum_j softmax_j * y_j). ----
template <int K>
__global__ __launch_bounds__(256) void attn_kernel(
    const float* __restrict__ xyz, const float* __restrict__ pf,
    const int* __restrict__ cidx,
    const unsigned short* __restrict__ idxS, const int* __restrict__ cntS,
    const float* __restrict__ wq, const float* __restrict__ wk,
    const float* __restrict__ wv, const float* __restrict__ wo,
    __hip_bfloat16* __restrict__ outA) {
  __shared__ float WqL[64*33], WkL[64*33], WvL[64*33], WoL[32*65];  // +1 pad rows
  __shared__ float xv[4][32];
  __shared__ float qv[4][64];
  __shared__ float yb[4][2][32];
  __shared__ float ov[4][64];
  __shared__ int cns[4];
  const int tid = threadIdx.x;
  const int wid = tid >> 6, lane = tid & 63;
  const int gid = blockIdx.x;
  const int b = gid >> 8;
  const int m = ((gid & 255) << 2) + wid;
  for (int i = tid; i < 2048; i += 256) {
    int r = i >> 5, c = i & 31;
    WqL[r*33 + c] = wq[i];
    WkL[r*33 + c] = wk[i];
    WvL[r*33 + c] = wv[i];
    int ro = i >> 6, co = i & 63;
    WoL[ro*65 + co] = wo[i];
  }
  if (lane < 32) {
    int ci = cidx[b * Mc + m] & (Npts - 1);
    xv[wid][lane] = sup_at(xyz, pf, b, lane, ci);
  }
  if (lane == 0) cns[wid] = cntS[b * Mc + m];
  __syncthreads();
  {
    float acc = 0.f;
#pragma unroll
    for (int c = 0; c < 32; ++c) acc = fmaf(WqL[lane*33 + c], xv[wid][c], acc);
    qv[wid][lane] = acc;
  }
  __syncthreads();
  int cnt = cns[wid];
  cnt = cnt < 1 ? 1 : (cnt > K ? K : cnt);
  const int jj = lane < K ? lane : 0;
  int nj = (int)idxS[((size_t)b*Mc + m)*K + jj] & (Npts - 1);
  float y[32];
#pragma unroll
  for (int c = 0; c < 32; ++c)
    y[c] = sup_at(xyz, pf, b, c, nj) - xv[wid][c];
  float w0 = 0.f, w1 = 0.f;
#pragma unroll 2
  for (int r = 0; r < 32; ++r) {
    float k0 = 0.f, k1 = 0.f;
#pragma unroll
    for (int c = 0; c < 32; ++c) {
      k0 = fmaf(WkL[r*33 + c], y[c], k0);
      k1 = fmaf(WkL[(r+32)*33 + c], y[c], k1);
    }
    w0 = fmaf(qv[wid][r], k0, w0);
    w1 = fmaf(qv[wid][r+32], k1, w1);
  }
  const float iscale = 0.17677669529663689f;  // 1/sqrt(32)
  w0 *= iscale; w1 *= iscale;
  if (lane >= cnt) { w0 = -1e9f; w1 = -1e9f; }
  float mx0 = w0, mx1 = w1;
#pragma unroll
  for (int d = K/2; d; d >>= 1) {
    mx0 = fmaxf(mx0, __shfl_xor(mx0, d, K));
    mx1 = fmaxf(mx1, __shfl_xor(mx1, d, K));
  }
  float e0 = __expf(w0 - mx0), e1 = __expf(w1 - mx1);
  float s0 = e0, s1 = e1;
#pragma unroll
  for (int d = K/2; d; d >>= 1) {
    s0 += __shfl_xor(s0, d, K);
    s1 += __shfl_xor(s1, d, K);
  }
  float wn0 = e0 / s0, wn1 = e1 / s1;
#pragma unroll
  for (int c = 0; c < 32; ++c) {
    float t0 = wn0 * y[c], t1 = wn1 * y[c];
#pragma unroll
    for (int d = K/2; d; d >>= 1) {
      t0 += __shfl_xor(t0, d, K);
      t1 += __shfl_xor(t1, d, K);
    }
    if (lane == 0) { yb[wid][0][c] = t0; yb[wid][1][c] = t1; }
  }
  __syncthreads();
  {
    const int h = lane >> 5;
    float a2 = 0.f;
#pragma unroll
    for (int c = 0; c < 32; ++c) a2 = fmaf(WvL[lane*33 + c], yb[wid][h][c], a2);
    ov[wid][lane] = a2;
  }
  __syncthreads();
  if (lane < 32) {
    float a3 = 0.f;
#pragma unroll
    for (int r = 0; r < 64; ++r) a3 = fmaf(WoL[lane*65 + r], ov[wid][r], a3);
    outA[((size_t)b*32 + lane)*Mc + m] = __float2bfloat16(a3 + xv[wid][lane]);
  }
}

// ---- K5: conv0 (64x32) + bias, BN stats via atomics ----
__global__ __launch_bounds__(256) void conv0_kernel(
    const __hip_bfloat16* __restrict__ inA, const float* __restrict__ w0,
    const float* __restrict__ b0, __hip_bfloat16* __restrict__ z0,
    float* __restrict__ ssum, float* __restrict__ ssq) {
  int idx = blockIdx.x * 256 + threadIdx.x;   // B*64*M
  int m = idx & (Mc - 1);
  int r = (idx >> 10) & 63;
  int b = idx >> 16;
  float acc = b0[r];
#pragma unroll
  for (int c = 0; c < 32; ++c)
    acc = fmaf(w0[r*32 + c], __bfloat162float(inA[((size_t)b*32 + c)*Mc + m]), acc);
  z0[((size_t)b*64 + r)*Mc + m] = __float2bfloat16(acc);
  float s = acc, q = acc * acc;
#pragma unroll
  for (int d = 32; d; d >>= 1) { s += __shfl_down(s, d, 64); q += __shfl_down(q, d, 64); }
  if ((threadIdx.x & 63) == 0) { atomicAdd(&ssum[r], s); atomicAdd(&ssq[r], q); }
}

// ---- K6: conv1 stats pass (folds bnfin0); optionally stores z1 f32 ----
__global__ __launch_bounds__(256) void conv1_stats_kernel(
    const __hip_bfloat16* __restrict__ z0,
    const float* __restrict__ ssum0, const float* __restrict__ ssq0,
    const float* __restrict__ g0, const float* __restrict__ t0,
    const float* __restrict__ w1, const float* __restrict__ b1,
    float* __restrict__ z1,                       // may be null
    float* __restrict__ ssum1, float* __restrict__ ssq1) {
  __shared__ float A0s[64], B0s[64];
  int tid = threadIdx.x;
  if (tid < 64) {
    float mu = ssum0[tid] * (1.0f/4096.0f);
    float var = ssq0[tid] * (1.0f/4096.0f) - mu * mu;
    if (var < 0.f) var = 0.f;
    float a = g0[tid] * rsqrtf(var + BN_EPS);
    A0s[tid] = a;
    B0s[tid] = t0[tid] - mu * a;
  }
  __syncthreads();
  int idx = blockIdx.x * 256 + tid;   // B*128*M
  int m = idx & (Mc - 1);
  int r2 = (idx >> 10) & 127;
  int b = idx >> 17;
  float acc = b1[r2];
#pragma unroll 8
  for (int r = 0; r < 64; ++r) {
    float u = fmaf(__bfloat162float(z0[((size_t)b*64 + r)*Mc + m]), A0s[r], B0s[r]);
    u = u > 0.f ? u : SLOPE * u;
    acc = fmaf(w1[r2*64 + r], u, acc);
  }
  if (z1) z1[idx] = acc;
  float s = acc, q = acc * acc;
#pragma unroll
  for (int d = 32; d; d >>= 1) { s += __shfl_down(s, d, 64); q += __shfl_down(q, d, 64); }
  if ((tid & 63) == 0) { atomicAdd(&ssum1[r2], s); atomicAdd(&ssq1[r2], q); }
}

// ---- K7: conv1 write pass (folds bnfin0+bnfin1); z1 path or recompute ----
__global__ __launch_bounds__(256) void conv1_write_kernel(
    const __hip_bfloat16* __restrict__ z0, const float* __restrict__ z1,
    const float* __restrict__ ssum0, const float* __restrict__ ssq0,
    const float* __restrict__ g0, const float* __restrict__ t0,
    const float* __restrict__ w1, const float* __restrict__ b1,
    const float* __restrict__ ssum1, const float* __restrict__ ssq1,
    const float* __restrict__ g1, const float* __restrict__ t1,
    float* __restrict__ outAll, int chOff, int out_size) {
  __shared__ float A0s[64], B0s[64];
  __shared__ float ab1[2];
  int tid = threadIdx.x;
  int idx = blockIdx.x * 256 + tid;   // B*128*M
  int m = idx & (Mc - 1);
  int r2 = (idx >> 10) & 127;         // uniform within block (256 | 1024)
  int b = idx >> 17;
  if (!z1 && tid < 64) {
    float mu = ssum0[tid] * (1.0f/4096.0f);
    float var = ssq0[tid] * (1.0f/4096.0f) - mu * mu;
    if (var < 0.f) var = 0.f;
    float a = g0[tid] * rsqrtf(var + BN_EPS);
    A0s[tid] = a;
    B0s[tid] = t0[tid] - mu * a;
  }
  if (tid == 0) {
    float mu = ssum1[r2] * (1.0f/4096.0f);
    float var = ssq1[r2] * (1.0f/4096.0f) - mu * mu;
    if (var < 0.f) var = 0.f;
    float a = g1[r2] * rsqrtf(var + BN_EPS);
    ab1[0] = a;
    ab1[1] = t1[r2] - mu * a;
  }
  __syncthreads();
  float acc;
  if (z1) {
    acc = z1[idx];
  } else {
    acc = b1[r2];
#pragma unroll 8
    for (int r = 0; r < 64; ++r) {
      float u = fmaf(__bfloat162float(z0[((size_t)b*64 + r)*Mc + m]), A0s[r], B0s[r]);
      u = u > 0.f ? u : SLOPE * u;
      acc = fmaf(w1[r2*64 + r], u, acc);
    }
  }
  float v = fmaf(acc, ab1[0], ab1[1]);
  size_t oidx = 12288 + ((size_t)b*256 + chOff + r2)*Mc + m;
  if (oidx < (size_t)out_size) outAll[oidx] = sanf(v, 777.0f);
}

extern "C" void kernel_launch(void* const* d_in, const int* in_sizes, int n_in,
                              void* d_out, int out_size, void* d_ws, size_t ws_size,
                              hipStream_t stream) {
  float* outb = (float*)d_out;
  int fillBlocks = (out_size + 255) / 256;
  if (n_in != 26 || in_sizes[0] != Bb*3*Npts || in_sizes[1] != Bb*29*Npts
      || in_sizes[2] != 2048) {
    fill_kernel<<<fillBlocks, 256, 0, stream>>>(outb, out_size, 7777.0f);
    return;
  }
  if (out_size != OUT_EXPECT) {
    fill_kernel<<<fillBlocks, 256, 0, stream>>>(outb, out_size, 23456.0f);
    return;
  }
  if (ws_size < WS_REQUIRED) {
    fill_kernel<<<fillBlocks, 256, 0, stream>>>(outb, out_size, 12345.0f);
    return;
  }
  const float* xyz = (const float*)d_in[0];
  const float* pf  = (const float*)d_in[1];
  char* ws = (char*)d_ws;
  int* cidx = (int*)(ws + OFF_CIDX);
  unsigned short* idx0 = (unsigned short*)(ws + OFF_IDX0);
  int* cnt0 = (int*)(ws + OFF_CNT0);
  unsigned short* idx1 = (unsigned short*)(ws + OFF_IDX1);
  int* cnt1 = (int*)(ws + OFF_CNT1);
  unsigned long long* fslots = (unsigned long long*)(ws + OFF_FSLOT);
  __hip_bfloat16* attn = (__hip_bfloat16*)(ws + OFF_ATTN);
  __hip_bfloat16* z0 = (__hip_bfloat16*)(ws + OFF_Z0);
  float* z1 = (ws_size >= WS_Z1_REQUIRED) ? (float*)(ws + OFF_Z1) : nullptr;

  hipMemsetAsync(ws, 0, ZERO_BYTES, stream);                 // stats etc
  hipMemsetAsync(ws + OFF_FSLOT, 0, FSLOT_BYTES, stream);    // fps val slots
  fps_kernel<<<Bb*NBLK, 512, 0, stream>>>(xyz, pf, cidx, fslots);
  ball_kernel<<<Bb*64, 256, 0, stream>>>(xyz, pf, cidx, idx0, cnt0, idx1, cnt1);

  for (int s = 0; s < 2; ++s) {
    const float* aq = (const float*)d_in[2 + s*12 + 0];
    const float* ak = (const float*)d_in[2 + s*12 + 1];
    const float* av = (const float*)d_in[2 + s*12 + 2];
    const float* ao = (const float*)d_in[2 + s*12 + 3];
    const float* w0 = (const float*)d_in[2 + s*12 + 4];
    const float* b0 = (const float*)d_in[2 + s*12 + 5];
    const float* g0 = (const float*)d_in[2 + s*12 + 6];
    const float* t0 = (const float*)d_in[2 + s*12 + 7];
    const float* w1 = (const float*)d_in[2 + s*12 + 8];
    const float* b1 = (const float*)d_in[2 + s*12 + 9];
    const float* g1 = (const float*)d_in[2 + s*12 + 10];
    const float* t1 = (const float*)d_in[2 + s*12 + 11];
    float* st = (float*)(ws + OFF_STATS) + (size_t)s*384;
    float *sum0 = st, *sq0 = st + 64, *sum1 = st + 128, *sq1 = st + 256;
    if (s == 0)
      attn_kernel<32><<<Bb*Mc/4, 256, 0, stream>>>(xyz, pf, cidx, idx0, cnt0, aq, ak, av, ao, attn);
    else
      attn_kernel<64><<<Bb*Mc/4, 256, 0, stream>>>(xyz, pf, cidx, idx1, cnt1, aq, ak, av, ao, attn);
    conv0_kernel<<<Bb*64*Mc/256, 256, 0, stream>>>(attn, w0, b0, z0, sum0, sq0);
    conv1_stats_kernel<<<Bb*128*Mc/256, 256, 0, stream>>>(z0, sum0, sq0, g0, t0,
                                                          w1, b1, z1, sum1, sq1);
    conv1_write_kernel<<<Bb*128*Mc/256, 256, 0, stream>>>(z0, z1, sum0, sq0, g0, t0,
                                                          w1, b1, sum1, sq1, g1, t1,
                                                          outb, s*128, out_size);
  }
  gather_kernel<<<48, 256, 0, stream>>>(xyz, cidx, outb, out_size);
}

// Round 15
// 2737.788 us; speedup vs baseline: 1.3152x; 1.0005x over previous
//
#include <hip/hip_runtime.h>
#include <hip/hip_bf16.h>

// PointNetMSG on MI355X. Inputs FP32, output FP32. Internal fp32, ws bf16.
// B=4, N=16384, Cs=32, M=1024, scales: (r=0.1,k=32),(r=0.2,k=64).
// R15: fps = R14 with ONE gated change — a point-major mirror supT[b][n][32]
// (built once) so the winner-feature gather reads 1-2 contiguous lines
// instead of 32 scattered 64KB-strided lines. Gated on ws_size (falls back
// to the exact R14 gather if ws < 12.2 MB). Tail unchanged from R12-R14.

static constexpr int Bb = 4;
static constexpr int Npts = 16384;
static constexpr int Mc = 1024;
static constexpr int NBLK = 16;                      // fps blocks per batch
static constexpr int OUT_EXPECT = 12288 + 1048576;   // new_xyz + feats
#define BN_EPS 1e-5f
#define SLOPE 0.02f
#define SCOPE_AGT __HIP_MEMORY_SCOPE_AGENT

// ---- workspace layout (base 1,687,552 B proven; z1 path 3,784,704 proven
// active in R13; supT path needs 12,173,312 — runtime-gated) ----
static constexpr size_t OFF_STATS = 33024;    // f32 [2][384]
static constexpr size_t ZERO_BYTES = 65536;
static constexpr size_t OFF_CIDX  = 65536;    // i32 [4][1024]
static constexpr size_t OFF_IDX0  = 81920;    // u16 [4][1024][32]
static constexpr size_t OFF_CNT0  = 344064;   // i32 [4][1024]
static constexpr size_t OFF_IDX1  = 360448;   // u16 [4][1024][64]
static constexpr size_t OFF_CNT1  = 884736;   // i32 [4][1024]
static constexpr size_t OFF_ATTN  = 901120;   // bf16 [4][32][1024]
static constexpr size_t OFF_Z0    = 1163264;  // bf16 [4][64][1024]
static constexpr size_t WS_REQUIRED = 1687552;
// fps val slots u64[4][1024][16] = 524288 B, aliased over attn/z0 (fps-only lifetime)
static constexpr size_t OFF_FSLOT = 901120;
static constexpr size_t FSLOT_BYTES = (size_t)Bb * Mc * NBLK * 8;
// optional z1 f32 [4][128][1024] = 2 MB beyond base layout (runtime-gated)
static constexpr size_t OFF_Z1 = 1687552;
static constexpr size_t WS_Z1_REQUIRED = OFF_Z1 + (size_t)Bb * 128 * Mc * 4;
// optional point-major mirror f32 [4][16384][32] = 8 MB (runtime-gated)
static constexpr size_t OFF_SUPT = WS_Z1_REQUIRED;
static constexpr size_t WS_T_REQUIRED = OFF_SUPT + (size_t)Bb * Npts * 32 * 4;

__device__ __forceinline__ float sup_at(const float* xyz, const float* pf,
                                        int b, int c, int n) {
  return (c < 3) ? xyz[((size_t)b*3 + c)*Npts + n]
                 : pf[((size_t)b*29 + (c-3))*Npts + n];
}

__device__ __forceinline__ float sanf(float v, float repl) {
  if (!(v == v) || fabsf(v) > 1e30f) v = repl;
  return v;
}

__global__ __launch_bounds__(256) void fill_kernel(float* out, int n, float val) {
  int i = blockIdx.x * 256 + threadIdx.x;
  if (i < n) out[i] = val;
}

// ---- K0 (gated): build point-major mirror supT[b][n][32] ----
__global__ __launch_bounds__(256) void buildT_kernel(
    const float* __restrict__ xyz, const float* __restrict__ pf,
    float* __restrict__ supT) {
  int idx = blockIdx.x * 256 + threadIdx.x;   // B*N
  int n = idx & (Npts - 1);
  int b = idx >> 14;
  float* dst = supT + ((size_t)b * Npts + n) * 32;
#pragma unroll
  for (int c = 0; c < 32; ++c) dst[c] = sup_at(xyz, pf, b, c, n);
}

// ---- K1: FPS (R14 frame; gather via supT when available).
// Distance arithmetic bit-identical to R6-R14 (sequential __fadd_rn chain).
__global__ __launch_bounds__(512, 2) void fps_kernel(
    const float* __restrict__ xyz, const float* __restrict__ pf,
    const float* __restrict__ supT,            // may be null
    int* __restrict__ cidx, unsigned long long* __restrict__ slots) {
  const int blk = blockIdx.x;
  const int b = blk >> 4;
  const int sb = blk & (NBLK - 1);
  const int tid = threadIdx.x;
  const int lane = tid & 63, wid = tid >> 6;
  float f0[32], f1[32];
  const int p0 = sb * 1024 + tid;
  const int p1 = p0 + 512;
  float d0 = 1e10f, d1 = 1e10f;
#pragma unroll
  for (int c = 0; c < 32; ++c) {
    f0[c] = sup_at(xyz, pf, b, c, p0);
    f1[c] = sup_at(xyz, pf, b, c, p1);
  }
  __shared__ float cf[32];
  __shared__ unsigned long long red[8];
  if (sb == 0 && tid == 0) cidx[b * Mc] = 0;
  if (tid < 32) cf[tid] = sup_at(xyz, pf, b, tid, 0);   // centroid 0 = point 0
  __syncthreads();
  unsigned long long* slotb = slots + (size_t)b * Mc * NBLK;   // [it][sb] packed layout
  const float* supTb = supT ? supT + (size_t)b * Npts * 32 : nullptr;
  for (int it = 0; it < Mc - 1; ++it) {
    // ---- local distance update (exact R6 arithmetic) ----
    float cc[32];
#pragma unroll
    for (int c = 0; c < 32; ++c) cc[c] = cf[c];
    {
      float d = 0.f, e = 0.f;
#pragma unroll
      for (int c = 0; c < 32; ++c) {
        float t0 = f0[c] - cc[c];
        float s0 = __fmul_rn(t0, t0);
        d = (c == 0) ? s0 : __fadd_rn(d, s0);
        float t1 = f1[c] - cc[c];
        float s1 = __fmul_rn(t1, t1);
        e = (c == 0) ? s1 : __fadd_rn(e, s1);
      }
      d0 = fminf(d0, d);
      d1 = fminf(d1, e);
    }
    float bd; int bp;
    if (d0 >= d1) { bd = d0; bp = p0; } else { bd = d1; bp = p1; }  // p0<p1: first-index tiebreak
    unsigned long long v =
        ((unsigned long long)__float_as_uint(bd) << 32) | (unsigned int)(~(unsigned int)bp);
#pragma unroll
    for (int d = 32; d; d >>= 1) {
      unsigned long long o = __shfl_xor(v, d, 64);
      if (o > v) v = o;
    }
    if (lane == 0) red[wid] = v;
    __syncthreads();
    if (tid == 0) {
      unsigned long long vb = red[0];
#pragma unroll
      for (int w = 1; w < 8; ++w) if (red[w] > vb) vb = red[w];
      atomicMax(&slotb[(size_t)it * NBLK + sb], vb);   // single publish, val != 0 always
    }
    // ---- wave 0: poll 16 val slots via concurrent LLC reads, pick winner ----
    if (wid == 0) {
      unsigned long long myv = 0;
      if (lane < NBLK) {
        const unsigned long long* sp = &slotb[(size_t)it * NBLK + lane];
        while ((myv = __hip_atomic_load(sp, __ATOMIC_RELAXED, SCOPE_AGT)) == 0ull)
          __builtin_amdgcn_s_sleep(1);
      }
      unsigned long long mv = myv;
#pragma unroll
      for (int d = 8; d; d >>= 1) {
        unsigned long long o = __shfl_xor(mv, d, 16);
        if (o > mv) mv = o;
      }
      unsigned long long vwin = __shfl(mv, 0, 64);
      int idxWin = (int)(~(unsigned int)(vwin & 0xffffffffu)) & (Npts - 1);
      if (lane < 32)
        cf[lane] = supTb ? supTb[(size_t)idxWin * 32 + lane]          // 1-2 lines
                         : sup_at(xyz, pf, b, lane, idxWin);          // 32 lines (fallback)
      if (lane == 0 && sb == 0) cidx[b * Mc + it + 1] = idxWin;
    }
    __syncthreads();
  }
}

// ---- K2 (runs last): new_xyz output, f32 ----
__global__ __launch_bounds__(256) void gather_kernel(
    const float* __restrict__ xyz, const int* __restrict__ cidx,
    float* __restrict__ oxyz, int out_size) {
  int idx = blockIdx.x * 256 + threadIdx.x;   // B*3*M = 12288
  if (idx >= out_size || idx >= 12288) return;
  int m = idx & (Mc - 1);
  int t = idx >> 10;          // b*3 + c
  int b = t / 3;
  int ci = cidx[b * Mc + m] & (Npts - 1);
  oxyz[idx] = sanf(xyz[(size_t)t * Npts + ci], 888.0f);
}

// ---- K3: ball grouping, both radii in one pass; u16 index lists ----
__global__ __launch_bounds__(256) void ball_kernel(
    const float* __restrict__ xyz, const float* __restrict__ pf,
    const int* __restrict__ cidx,
    unsigned short* __restrict__ idx0, int* __restrict__ cnt0,
    unsigned short* __restrict__ idx1, int* __restrict__ cnt1) {
  const int b = blockIdx.x >> 6;
  const int mt = blockIdx.x & 63;
  const int tid = threadIdx.x;
  __shared__ float cf[16][32];
  __shared__ float csq[16];
  __shared__ unsigned int ent[16][128];
  __shared__ int lcnt[16];
  for (int i = tid; i < 16 * 32; i += 256) {
    int ml = i >> 5, c = i & 31;
    int ci = cidx[b * Mc + mt * 16 + ml] & (Npts - 1);
    cf[ml][c] = sup_at(xyz, pf, b, c, ci);
  }
  if (tid < 16) lcnt[tid] = 0;
  __syncthreads();
  if (tid < 16) {
    float a = 0.f;
#pragma unroll
    for (int c = 0; c < 32; ++c) a = fmaf(cf[tid][c], cf[tid][c], a);
    csq[tid] = a;
  }
  __syncthreads();
  for (int ch = 0; ch < Npts / 256; ++ch) {
    int p = ch * 256 + tid;
    float x[32];
#pragma unroll
    for (int c = 0; c < 32; ++c) x[c] = sup_at(xyz, pf, b, c, p);
    float sp = 0.f;
#pragma unroll
    for (int c = 0; c < 32; ++c) sp = fmaf(x[c], x[c], sp);
#pragma unroll 4
    for (int ml = 0; ml < 16; ++ml) {
      float dot = 0.f;
#pragma unroll
      for (int c = 0; c < 32; ++c) dot = fmaf(cf[ml][c], x[c], dot);
      float d = sp - 2.0f * dot + csq[ml];
      if (d <= 0.04f) {
        int pos = atomicAdd(&lcnt[ml], 1);
        if (pos < 128) ent[ml][pos] = (unsigned int)p | (d <= 0.01f ? 0x80000000u : 0u);
      }
    }
  }
  __syncthreads();
  if (tid < 16) {
    int ml = tid;
    int nn = lcnt[ml]; if (nn > 128) nn = 128;
    for (int i = 1; i < nn; ++i) {   // insertion sort by point index ascending
      unsigned int e = ent[ml][i]; unsigned int key = e & 0x7fffffffu;
      int j = i - 1;
      while (j >= 0 && (ent[ml][j] & 0x7fffffffu) > key) { ent[ml][j+1] = ent[ml][j]; --j; }
      ent[ml][j+1] = e;
    }
    int gm = b * Mc + mt * 16 + ml;
    int c1 = nn < 64 ? nn : 64;
    unsigned short first1 = nn > 0 ? (unsigned short)(ent[ml][0] & 0x7fffffffu) : 0;
    unsigned short* o1 = idx1 + (size_t)gm * 64;
    for (int j = 0; j < 64; ++j)
      o1[j] = j < c1 ? (unsigned short)(ent[ml][j] & 0x7fffffffu) : first1;
    cnt1[gm] = c1;
    unsigned short* o0 = idx0 + (size_t)gm * 32;
    int c0 = 0; unsigned short first0 = 0;
    for (int i = 0; i < nn && c0 < 32; ++i) {
      if (ent[ml][i] & 0x80000000u) {
        unsigned short nv = (unsigned short)(ent[ml][i] & 0x7fffffffu);
        if (c0 == 0) first0 = nv;
        o0[c0++] = nv;
      }
    }
    for (int j = c0; j < 32; ++j) o0[j] = first0;
    cnt0[gm] = c0;
  }
}

// ---- K4: attention, one wave per centroid. o = Wv @ (sum_j softmax_j * y_j). ----
template <int K>
__global__ __launch_bounds__(256) void attn_kernel(
    const float* __restrict__ xyz, const float* __restrict__ pf,
    const int* __restrict__ cidx,
    const unsigned short* __restrict__ idxS, const int* __restrict__ cntS,
    const float* __restrict__ wq, const float* __restrict__ wk,
    const float* __restrict__ wv, const float* __restrict__ wo,
    __hip_bfloat16* __restrict__ outA) {
  __shared__ float WqL[64*33], WkL[64*33], WvL[64*33], WoL[32*65];  // +1 pad rows
  __shared__ float xv[4][32];
  __shared__ float qv[4][64];
  __shared__ float yb[4][2][32];
  __shared__ float ov[4][64];
  __shared__ int cns[4];
  const int tid = threadIdx.x;
  const int wid = tid >> 6, lane = tid & 63;
  const int gid = blockIdx.x;
  const int b = gid >> 8;
  const int m = ((gid & 255) << 2) + wid;
  for (int i = tid; i < 2048; i += 256) {
    int r = i >> 5, c = i & 31;
    WqL[r*33 + c] = wq[i];
    WkL[r*33 + c] = wk[i];
    WvL[r*33 + c] = wv[i];
    int ro = i >> 6, co = i & 63;
    WoL[ro*65 + co] = wo[i];
  }
  if (lane < 32) {
    int ci = cidx[b * Mc + m] & (Npts - 1);
    xv[wid][lane] = sup_at(xyz, pf, b, lane, ci);
  }
  if (lane == 0) cns[wid] = cntS[b * Mc + m];
  __syncthreads();
  {
    float acc = 0.f;
#pragma unroll
    for (int c = 0; c < 32; ++c) acc = fmaf(WqL[lane*33 + c], xv[wid][c], acc);
    qv[wid][lane] = acc;
  }
  __syncthreads();
  int cnt = cns[wid];
  cnt = cnt < 1 ? 1 : (cnt > K ? K : cnt);
  const int jj = lane < K ? lane : 0;
  int nj = (int)idxS[((size_t)b*Mc + m)*K + jj] & (Npts - 1);
  float y[32];
#pragma unroll
  for (int c = 0; c < 32; ++c)
    y[c] = sup_at(xyz, pf, b, c, nj) - xv[wid][c];
  float w0 = 0.f, w1 = 0.f;
#pragma unroll 2
  for (int r = 0; r < 32; ++r) {
    float k0 = 0.f, k1 = 0.f;
#pragma unroll
    for (int c = 0; c < 32; ++c) {
      k0 = fmaf(WkL[r*33 + c], y[c], k0);
      k1 = fmaf(WkL[(r+32)*33 + c], y[c], k1);
    }
    w0 = fmaf(qv[wid][r], k0, w0);
    w1 = fmaf(qv[wid][r+32], k1, w1);
  }
  const float iscale = 0.17677669529663689f;  // 1/sqrt(32)
  w0 *= iscale; w1 *= iscale;
  if (lane >= cnt) { w0 = -1e9f; w1 = -1e9f; }
  float mx0 = w0, mx1 = w1;
#pragma unroll
  for (int d = K/2; d; d >>= 1) {
    mx0 = fmaxf(mx0, __shfl_xor(mx0, d, K));
    mx1 = fmaxf(mx1, __shfl_xor(mx1, d, K));
  }
  float e0 = __expf(w0 - mx0), e1 = __expf(w1 - mx1);
  float s0 = e0, s1 = e1;
#pragma unroll
  for (int d = K/2; d; d >>= 1) {
    s0 += __shfl_xor(s0, d, K);
    s1 += __shfl_xor(s1, d, K);
  }
  float wn0 = e0 / s0, wn1 = e1 / s1;
#pragma unroll
  for (int c = 0; c < 32; ++c) {
    float t0 = wn0 * y[c], t1 = wn1 * y[c];
#pragma unroll
    for (int d = K/2; d; d >>= 1) {
      t0 += __shfl_xor(t0, d, K);
      t1 += __shfl_xor(t1, d, K);
    }
    if (lane == 0) { yb[wid][0][c] = t0; yb[wid][1][c] = t1; }
  }
  __syncthreads();
  {
    const int h = lane >> 5;
    float a2 = 0.f;
#pragma unroll
    for (int c = 0; c < 32; ++c) a2 = fmaf(WvL[lane*33 + c], yb[wid][h][c], a2);
    ov[wid][lane] = a2;
  }
  __syncthreads();
  if (lane < 32) {
    float a3 = 0.f;
#pragma unroll
    for (int r = 0; r < 64; ++r) a3 = fmaf(WoL[lane*65 + r], ov[wid][r], a3);
    outA[((size_t)b*32 + lane)*Mc + m] = __float2bfloat16(a3 + xv[wid][lane]);
  }
}

// ---- K5: conv0 (64x32) + bias, BN stats via atomics ----
__global__ __launch_bounds__(256) void conv0_kernel(
    const __hip_bfloat16* __restrict__ inA, const float* __restrict__ w0,
    const float* __restrict__ b0, __hip_bfloat16* __restrict__ z0,
    float* __restrict__ ssum, float* __restrict__ ssq) {
  int idx = blockIdx.x * 256 + threadIdx.x;   // B*64*M
  int m = idx & (Mc - 1);
  int r = (idx >> 10) & 63;
  int b = idx >> 16;
  float acc = b0[r];
#pragma unroll
  for (int c = 0; c < 32; ++c)
    acc = fmaf(w0[r*32 + c], __bfloat162float(inA[((size_t)b*32 + c)*Mc + m]), acc);
  z0[((size_t)b*64 + r)*Mc + m] = __float2bfloat16(acc);
  float s = acc, q = acc * acc;
#pragma unroll
  for (int d = 32; d; d >>= 1) { s += __shfl_down(s, d, 64); q += __shfl_down(q, d, 64); }
  if ((threadIdx.x & 63) == 0) { atomicAdd(&ssum[r], s); atomicAdd(&ssq[r], q); }
}

// ---- K6: conv1 stats pass (folds bnfin0); optionally stores z1 f32 ----
__global__ __launch_bounds__(256) void conv1_stats_kernel(
    const __hip_bfloat16* __restrict__ z0,
    const float* __restrict__ ssum0, const float* __restrict__ ssq0,
    const float* __restrict__ g0, const float* __restrict__ t0,
    const float* __restrict__ w1, const float* __restrict__ b1,
    float* __restrict__ z1,                       // may be null
    float* __restrict__ ssum1, float* __restrict__ ssq1) {
  __shared__ float A0s[64], B0s[64];
  int tid = threadIdx.x;
  if (tid < 64) {
    float mu = ssum0[tid] * (1.0f/4096.0f);
    float var = ssq0[tid] * (1.0f/4096.0f) - mu * mu;
    if (var < 0.f) var = 0.f;
    float a = g0[tid] * rsqrtf(var + BN_EPS);
    A0s[tid] = a;
    B0s[tid] = t0[tid] - mu * a;
  }
  __syncthreads();
  int idx = blockIdx.x * 256 + tid;   // B*128*M
  int m = idx & (Mc - 1);
  int r2 = (idx >> 10) & 127;
  int b = idx >> 17;
  float acc = b1[r2];
#pragma unroll 8
  for (int r = 0; r < 64; ++r) {
    float u = fmaf(__bfloat162float(z0[((size_t)b*64 + r)*Mc + m]), A0s[r], B0s[r]);
    u = u > 0.f ? u : SLOPE * u;
    acc = fmaf(w1[r2*64 + r], u, acc);
  }
  if (z1) z1[idx] = acc;
  float s = acc, q = acc * acc;
#pragma unroll
  for (int d = 32; d; d >>= 1) { s += __shfl_down(s, d, 64); q += __shfl_down(q, d, 64); }
  if ((tid & 63) == 0) { atomicAdd(&ssum1[r2], s); atomicAdd(&ssq1[r2], q); }
}

// ---- K7: conv1 write pass (folds bnfin0+bnfin1); z1 path or recompute ----
__global__ __launch_bounds__(256) void conv1_write_kernel(
    const __hip_bfloat16* __restrict__ z0, const float* __restrict__ z1,
    const float* __restrict__ ssum0, const float* __restrict__ ssq0,
    const float* __restrict__ g0, const float* __restrict__ t0,
    const float* __restrict__ w1, const float* __restrict__ b1,
    const float* __restrict__ ssum1, const float* __restrict__ ssq1,
    const float* __restrict__ g1, const float* __restrict__ t1,
    float* __restrict__ outAll, int chOff, int out_size) {
  __shared__ float A0s[64], B0s[64];
  __shared__ float ab1[2];
  int tid = threadIdx.x;
  int idx = blockIdx.x * 256 + tid;   // B*128*M
  int m = idx & (Mc - 1);
  int r2 = (idx >> 10) & 127;         // uniform within block (256 | 1024)
  int b = idx >> 17;
  if (!z1 && tid < 64) {
    float mu = ssum0[tid] * (1.0f/4096.0f);
    float var = ssq0[tid] * (1.0f/4096.0f) - mu * mu;
    if (var < 0.f) var = 0.f;
    float a = g0[tid] * rsqrtf(var + BN_EPS);
    A0s[tid] = a;
    B0s[tid] = t0[tid] - mu * a;
  }
  if (tid == 0) {
    float mu = ssum1[r2] * (1.0f/4096.0f);
    float var = ssq1[r2] * (1.0f/4096.0f) - mu * mu;
    if (var < 0.f) var = 0.f;
    float a = g1[r2] * rsqrtf(var + BN_EPS);
    ab1[0] = a;
    ab1[1] = t1[r2] - mu * a;
  }
  __syncthreads();
  float acc;
  if (z1) {
    acc = z1[idx];
  } else {
    acc = b1[r2];
#pragma unroll 8
    for (int r = 0; r < 64; ++r) {
      float u = fmaf(__bfloat162float(z0[((size_t)b*64 + r)*Mc + m]), A0s[r], B0s[r]);
      u = u > 0.f ? u : SLOPE * u;
      acc = fmaf(w1[r2*64 + r], u, acc);
    }
  }
  float v = fmaf(acc, ab1[0], ab1[1]);
  size_t oidx = 12288 + ((size_t)b*256 + chOff + r2)*Mc + m;
  if (oidx < (size_t)out_size) outAll[oidx] = sanf(v, 777.0f);
}

extern "C" void kernel_launch(void* const* d_in, const int* in_sizes, int n_in,
                              void* d_out, int out_size, void* d_ws, size_t ws_size,
                              hipStream_t stream) {
  float* outb = (float*)d_out;
  int fillBlocks = (out_size + 255) / 256;
  if (n_in != 26 || in_sizes[0] != Bb*3*Npts || in_sizes[1] != Bb*29*Npts
      || in_sizes[2] != 2048) {
    fill_kernel<<<fillBlocks, 256, 0, stream>>>(outb, out_size, 7777.0f);
    return;
  }
  if (out_size != OUT_EXPECT) {
    fill_kernel<<<fillBlocks, 256, 0, stream>>>(outb, out_size, 23456.0f);
    return;
  }
  if (ws_size < WS_REQUIRED) {
    fill_kernel<<<fillBlocks, 256, 0, stream>>>(outb, out_size, 12345.0f);
    return;
  }
  const float* xyz = (const float*)d_in[0];
  const float* pf  = (const float*)d_in[1];
  char* ws = (char*)d_ws;
  int* cidx = (int*)(ws + OFF_CIDX);
  unsigned short* idx0 = (unsigned short*)(ws + OFF_IDX0);
  int* cnt0 = (int*)(ws + OFF_CNT0);
  unsigned short* idx1 = (unsigned short*)(ws + OFF_IDX1);
  int* cnt1 = (int*)(ws + OFF_CNT1);
  unsigned long long* fslots = (unsigned long long*)(ws + OFF_FSLOT);
  __hip_bfloat16* attn = (__hip_bfloat16*)(ws + OFF_ATTN);
  __hip_bfloat16* z0 = (__hip_bfloat16*)(ws + OFF_Z0);
  float* z1 = (ws_size >= WS_Z1_REQUIRED) ? (float*)(ws + OFF_Z1) : nullptr;
  float* supT = (ws_size >= WS_T_REQUIRED) ? (float*)(ws + OFF_SUPT) : nullptr;

  hipMemsetAsync(ws, 0, ZERO_BYTES, stream);                 // stats etc
  hipMemsetAsync(ws + OFF_FSLOT, 0, FSLOT_BYTES, stream);    // fps val slots
  if (supT) buildT_kernel<<<Bb*Npts/256, 256, 0, stream>>>(xyz, pf, supT);
  fps_kernel<<<Bb*NBLK, 512, 0, stream>>>(xyz, pf, supT, cidx, fslots);
  ball_kernel<<<Bb*64, 256, 0, stream>>>(xyz, pf, cidx, idx0, cnt0, idx1, cnt1);

  for (int s = 0; s < 2; ++s) {
    const float* aq = (const float*)d_in[2 + s*12 + 0];
    const float* ak = (const float*)d_in[2 + s*12 + 1];
    const float* av = (const float*)d_in[2 + s*12 + 2];
    const float* ao = (const float*)d_in[2 + s*12 + 3];
    const float* w0 = (const float*)d_in[2 + s*12 + 4];
    const float* b0 = (const float*)d_in[2 + s*12 + 5];
    const float* g0 = (const float*)d_in[2 + s*12 + 6];
    const float* t0 = (const float*)d_in[2 + s*12 + 7];
    const float* w1 = (const float*)d_in[2 + s*12 + 8];
    const float* b1 = (const float*)d_in[2 + s*12 + 9];
    const float* g1 = (const float*)d_in[2 + s*12 + 10];
    const float* t1 = (const float*)d_in[2 + s*12 + 11];
    float* st = (float*)(ws + OFF_STATS) + (size_t)s*384;
    float *sum0 = st, *sq0 = st + 64, *sum1 = st + 128, *sq1 = st + 256;
    if (s == 0)
      attn_kernel<32><<<Bb*Mc/4, 256, 0, stream>>>(xyz, pf, cidx, idx0, cnt0, aq, ak, av, ao, attn);
    else
      attn_kernel<64><<<Bb*Mc/4, 256, 0, stream>>>(xyz, pf, cidx, idx1, cnt1, aq, ak, av, ao, attn);
    conv0_kernel<<<Bb*64*Mc/256, 256, 0, stream>>>(attn, w0, b0, z0, sum0, sq0);
    conv1_stats_kernel<<<Bb*128*Mc/256, 256, 0, stream>>>(z0, sum0, sq0, g0, t0,
                                                          w1, b1, z1, sum1, sq1);
    conv1_write_kernel<<<Bb*128*Mc/256, 256, 0, stream>>>(z0, z1, sum0, sq0, g0, t0,
                                                          w1, b1, sum1, sq1, g1, t1,
                                                          outb, s*128, out_size);
  }
  gather_kernel<<<48, 256, 0, stream>>>(xyz, cidx, outb, out_size);
}

// Round 16
// 2688.981 us; speedup vs baseline: 1.3391x; 1.0182x over previous
//
#include <hip/hip_runtime.h>
#include <hip/hip_bf16.h>

// PointNetMSG on MI355X. Inputs FP32, output FP32. Internal fp32.
// B=4, N=16384, Cs=32, M=1024, scales: (r=0.1,k=32),(r=0.2,k=64).
// R16: ball grouping fused INTO the fps launch as streaming consumer blocks
// (192-block merged kernel: 64 fps producers + 128 ballpoint consumers that
// poll cidx sentinels and process centroids as they arrive on otherwise-idle
// CUs). fps protocol itself = R11/R14/R15 floor (untouched). attn gathers
// point rows from supT (coalesced). Gated on ws>=12.17MB (proven R15);
// full R15 fallback retained.

static constexpr int Bb = 4;
static constexpr int Npts = 16384;
static constexpr int Mc = 1024;
static constexpr int NBLK = 16;                      // fps blocks per batch
static constexpr int OUT_EXPECT = 12288 + 1048576;   // new_xyz + feats
#define BN_EPS 1e-5f
#define SLOPE 0.02f
#define SCOPE_AGT __HIP_MEMORY_SCOPE_AGENT

// ---- workspace layout ----
static constexpr size_t OFF_STATS = 33024;    // f32 [2][384]
static constexpr size_t OFF_GCNT  = 40960;    // u32 [4][1024] (zeroed)
static constexpr size_t ZERO_BYTES = 65536;
static constexpr size_t OFF_CIDX  = 65536;    // u32 [4][1024] (memset 0xFF)
static constexpr size_t OFF_IDX0  = 81920;    // u16 [4][1024][32]
static constexpr size_t OFF_CNT0  = 344064;   // i32 [4][1024]
static constexpr size_t OFF_IDX1  = 360448;   // u16 [4][1024][64]
static constexpr size_t OFF_CNT1  = 884736;   // i32 [4][1024]
static constexpr size_t OFF_ATTN  = 901120;   // bf16 [4][32][1024]
static constexpr size_t OFF_Z0    = 1163264;  // bf16 [4][64][1024]
static constexpr size_t WS_REQUIRED = 1687552;
// fps val slots u64[4][1024][16] = 512 KB, aliased over attn/z0 (fps-only lifetime)
static constexpr size_t OFF_FSLOT = 901120;
static constexpr size_t FSLOT_BYTES = (size_t)Bb * Mc * NBLK * 8;
// z1 f32 [4][128][1024] = 2 MB; ALSO aliased by gent u32[4][1024][128] = 2 MB
// (gent consumed by ballpost before conv1_stats writes z1 — disjoint lifetimes)
static constexpr size_t OFF_Z1 = 1687552;
static constexpr size_t OFF_GENT = OFF_Z1;
static constexpr size_t WS_Z1_REQUIRED = OFF_Z1 + (size_t)Bb * 128 * Mc * 4;
// point-major mirror f32 [4][16384][32] = 8 MB (proven active in R15)
static constexpr size_t OFF_SUPT = WS_Z1_REQUIRED;
static constexpr size_t WS_T_REQUIRED = OFF_SUPT + (size_t)Bb * Npts * 32 * 4;

__device__ __forceinline__ float sup_at(const float* xyz, const float* pf,
                                        int b, int c, int n) {
  return (c < 3) ? xyz[((size_t)b*3 + c)*Npts + n]
                 : pf[((size_t)b*29 + (c-3))*Npts + n];
}

__device__ __forceinline__ float sanf(float v, float repl) {
  if (!(v == v) || fabsf(v) > 1e30f) v = repl;
  return v;
}

__global__ __launch_bounds__(256) void fill_kernel(float* out, int n, float val) {
  int i = blockIdx.x * 256 + threadIdx.x;
  if (i < n) out[i] = val;
}

// ---- K0: build point-major mirror supT[b][n][32] ----
__global__ __launch_bounds__(256) void buildT_kernel(
    const float* __restrict__ xyz, const float* __restrict__ pf,
    float* __restrict__ supT) {
  int idx = blockIdx.x * 256 + threadIdx.x;   // B*N
  int n = idx & (Npts - 1);
  int b = idx >> 14;
  float* dst = supT + ((size_t)b * Npts + n) * 32;
#pragma unroll
  for (int c = 0; c < 32; ++c) dst[c] = sup_at(xyz, pf, b, c, n);
}

// ---- K1 (merged): blocks 0..63 = fps producers (R15-identical protocol,
// cidx published via atomicExch); blocks 64..191 = ballpoint consumers.
__global__ __launch_bounds__(512, 2) void fps_ball_kernel(
    const float* __restrict__ xyz, const float* __restrict__ pf,
    const float* __restrict__ supT,
    unsigned int* __restrict__ cidx, unsigned long long* __restrict__ slots,
    unsigned int* __restrict__ gcnt, unsigned int* __restrict__ gent) {
  const int tid = threadIdx.x;
  if (blockIdx.x < 64) {
    // ================= fps producer role =================
    const int blk = blockIdx.x;
    const int b = blk >> 4;
    const int sb = blk & (NBLK - 1);
    const int lane = tid & 63, wid = tid >> 6;
    float f0[32], f1[32];
    const int p0 = sb * 1024 + tid;
    const int p1 = p0 + 512;
    float d0 = 1e10f, d1 = 1e10f;
#pragma unroll
    for (int c = 0; c < 32; ++c) {
      f0[c] = sup_at(xyz, pf, b, c, p0);
      f1[c] = sup_at(xyz, pf, b, c, p1);
    }
    __shared__ float cf[32];
    __shared__ unsigned long long red[8];
    if (sb == 0 && tid == 0) atomicExch(&cidx[b * Mc], 0u);
    if (tid < 32) cf[tid] = sup_at(xyz, pf, b, tid, 0);   // centroid 0 = point 0
    __syncthreads();
    unsigned long long* slotb = slots + (size_t)b * Mc * NBLK;   // [it][sb] packed
    const float* supTb = supT + (size_t)b * Npts * 32;
    for (int it = 0; it < Mc - 1; ++it) {
      float cc[32];
#pragma unroll
      for (int c = 0; c < 32; ++c) cc[c] = cf[c];
      {
        float d = 0.f, e = 0.f;
#pragma unroll
        for (int c = 0; c < 32; ++c) {
          float t0 = f0[c] - cc[c];
          float s0 = __fmul_rn(t0, t0);
          d = (c == 0) ? s0 : __fadd_rn(d, s0);
          float t1 = f1[c] - cc[c];
          float s1 = __fmul_rn(t1, t1);
          e = (c == 0) ? s1 : __fadd_rn(e, s1);
        }
        d0 = fminf(d0, d);
        d1 = fminf(d1, e);
      }
      float bd; int bp;
      if (d0 >= d1) { bd = d0; bp = p0; } else { bd = d1; bp = p1; }
      unsigned long long v =
          ((unsigned long long)__float_as_uint(bd) << 32) | (unsigned int)(~(unsigned int)bp);
#pragma unroll
      for (int d = 32; d; d >>= 1) {
        unsigned long long o = __shfl_xor(v, d, 64);
        if (o > v) v = o;
      }
      if (lane == 0) red[wid] = v;
      __syncthreads();
      if (tid == 0) {
        unsigned long long vb = red[0];
#pragma unroll
        for (int w = 1; w < 8; ++w) if (red[w] > vb) vb = red[w];
        atomicMax(&slotb[(size_t)it * NBLK + sb], vb);
      }
      if (wid == 0) {
        unsigned long long myv = 0;
        if (lane < NBLK) {
          const unsigned long long* sp = &slotb[(size_t)it * NBLK + lane];
          while ((myv = __hip_atomic_load(sp, __ATOMIC_RELAXED, SCOPE_AGT)) == 0ull)
            __builtin_amdgcn_s_sleep(1);
        }
        unsigned long long mv = myv;
#pragma unroll
        for (int d = 8; d; d >>= 1) {
          unsigned long long o = __shfl_xor(mv, d, 16);
          if (o > mv) mv = o;
        }
        unsigned long long vwin = __shfl(mv, 0, 64);
        int idxWin = (int)(~(unsigned int)(vwin & 0xffffffffu)) & (Npts - 1);
        if (lane < 32) cf[lane] = supTb[(size_t)idxWin * 32 + lane];
        if (lane == 0 && sb == 0)
          atomicExch(&cidx[b * Mc + it + 1], (unsigned int)idxWin);
      }
      __syncthreads();
    }
  } else {
    // ================= ballpoint consumer role =================
    const int blk2 = blockIdx.x - 64;
    const int b = blk2 >> 5;          // 32 blocks per batch
    const int chunk = blk2 & 31;
    const int p = chunk * 512 + tid;
    const float* supTb = supT + (size_t)b * Npts * 32;
    float x[32];
    const float* srow = supTb + (size_t)p * 32;
#pragma unroll
    for (int c = 0; c < 32; ++c) x[c] = srow[c];
    float sp = 0.f;
#pragma unroll
    for (int c = 0; c < 32; ++c) sp = fmaf(x[c], x[c], sp);
    __shared__ float cfb[2][32];
    unsigned int* cidxb = cidx + b * Mc;
    unsigned int* gcntb = gcnt + b * Mc;
    unsigned int* gentb = gent + (size_t)b * Mc * 128;
    for (int m = 0; m < Mc; ++m) {
      if (tid < 32) {
        unsigned int ci;
        const unsigned int* cp = &cidxb[m];
        while ((ci = __hip_atomic_load(cp, __ATOMIC_RELAXED, SCOPE_AGT)) == 0xFFFFFFFFu)
          __builtin_amdgcn_s_sleep(2);
        cfb[m & 1][tid] = supTb[(size_t)(ci & (Npts - 1)) * 32 + tid];
      }
      __syncthreads();
      const float* cfm = cfb[m & 1];
      float csq = 0.f, dot = 0.f;
#pragma unroll
      for (int c = 0; c < 32; ++c) {
        csq = fmaf(cfm[c], cfm[c], csq);
        dot = fmaf(cfm[c], x[c], dot);
      }
      float d = sp - 2.0f * dot + csq;
      if (d <= 0.04f) {
        int pos = atomicAdd(&gcntb[m], 1u);
        if (pos < 128)
          gentb[(size_t)m * 128 + pos] = (unsigned int)p | (d <= 0.01f ? 0x80000000u : 0u);
      }
    }
  }
}

// ---- K1b: ballpost — sort per-centroid hit lists, emit idx/cnt (old semantics) ----
__global__ __launch_bounds__(256) void ballpost_kernel(
    unsigned int* __restrict__ gcnt, unsigned int* __restrict__ gent,
    unsigned short* __restrict__ idx0, int* __restrict__ cnt0,
    unsigned short* __restrict__ idx1, int* __restrict__ cnt1) {
  int idx = blockIdx.x * 256 + threadIdx.x;   // B*M = 4096
  int b = idx >> 10;
  int m = idx & (Mc - 1);
  int gm = b * Mc + m;
  unsigned int* e = gent + (size_t)gm * 128;
  int nn = (int)gcnt[gm]; if (nn > 128) nn = 128;
  for (int i = 1; i < nn; ++i) {   // insertion sort by point index ascending
    unsigned int ei = e[i]; unsigned int key = ei & 0x7fffffffu;
    int j = i - 1;
    while (j >= 0 && (e[j] & 0x7fffffffu) > key) { e[j+1] = e[j]; --j; }
    e[j+1] = ei;
  }
  int c1 = nn < 64 ? nn : 64;
  unsigned short first1 = nn > 0 ? (unsigned short)(e[0] & 0x7fffffffu) : 0;
  unsigned short* o1 = idx1 + (size_t)gm * 64;
  for (int j = 0; j < 64; ++j)
    o1[j] = j < c1 ? (unsigned short)(e[j] & 0x7fffffffu) : first1;
  cnt1[gm] = c1;
  unsigned short* o0 = idx0 + (size_t)gm * 32;
  int c0 = 0; unsigned short first0 = 0;
  for (int i = 0; i < nn && c0 < 32; ++i) {
    if (e[i] & 0x80000000u) {
      unsigned short nv = (unsigned short)(e[i] & 0x7fffffffu);
      if (c0 == 0) first0 = nv;
      o0[c0++] = nv;
    }
  }
  for (int j = c0; j < 32; ++j) o0[j] = first0;
  cnt0[gm] = c0;
}

// ---- fallback fps (R15) ----
__global__ __launch_bounds__(512, 2) void fps_kernel(
    const float* __restrict__ xyz, const float* __restrict__ pf,
    const float* __restrict__ supT,            // may be null
    int* __restrict__ cidx, unsigned long long* __restrict__ slots) {
  const int blk = blockIdx.x;
  const int b = blk >> 4;
  const int sb = blk & (NBLK - 1);
  const int tid = threadIdx.x;
  const int lane = tid & 63, wid = tid >> 6;
  float f0[32], f1[32];
  const int p0 = sb * 1024 + tid;
  const int p1 = p0 + 512;
  float d0 = 1e10f, d1 = 1e10f;
#pragma unroll
  for (int c = 0; c < 32; ++c) {
    f0[c] = sup_at(xyz, pf, b, c, p0);
    f1[c] = sup_at(xyz, pf, b, c, p1);
  }
  __shared__ float cf[32];
  __shared__ unsigned long long red[8];
  if (sb == 0 && tid == 0) cidx[b * Mc] = 0;
  if (tid < 32) cf[tid] = sup_at(xyz, pf, b, tid, 0);
  __syncthreads();
  unsigned long long* slotb = slots + (size_t)b * Mc * NBLK;
  const float* supTb = supT ? supT + (size_t)b * Npts * 32 : nullptr;
  for (int it = 0; it < Mc - 1; ++it) {
    float cc[32];
#pragma unroll
    for (int c = 0; c < 32; ++c) cc[c] = cf[c];
    {
      float d = 0.f, e = 0.f;
#pragma unroll
      for (int c = 0; c < 32; ++c) {
        float t0 = f0[c] - cc[c];
        float s0 = __fmul_rn(t0, t0);
        d = (c == 0) ? s0 : __fadd_rn(d, s0);
        float t1 = f1[c] - cc[c];
        float s1 = __fmul_rn(t1, t1);
        e = (c == 0) ? s1 : __fadd_rn(e, s1);
      }
      d0 = fminf(d0, d);
      d1 = fminf(d1, e);
    }
    float bd; int bp;
    if (d0 >= d1) { bd = d0; bp = p0; } else { bd = d1; bp = p1; }
    unsigned long long v =
        ((unsigned long long)__float_as_uint(bd) << 32) | (unsigned int)(~(unsigned int)bp);
#pragma unroll
    for (int d = 32; d; d >>= 1) {
      unsigned long long o = __shfl_xor(v, d, 64);
      if (o > v) v = o;
    }
    if (lane == 0) red[wid] = v;
    __syncthreads();
    if (tid == 0) {
      unsigned long long vb = red[0];
#pragma unroll
      for (int w = 1; w < 8; ++w) if (red[w] > vb) vb = red[w];
      atomicMax(&slotb[(size_t)it * NBLK + sb], vb);
    }
    if (wid == 0) {
      unsigned long long myv = 0;
      if (lane < NBLK) {
        const unsigned long long* sp = &slotb[(size_t)it * NBLK + lane];
        while ((myv = __hip_atomic_load(sp, __ATOMIC_RELAXED, SCOPE_AGT)) == 0ull)
          __builtin_amdgcn_s_sleep(1);
      }
      unsigned long long mv = myv;
#pragma unroll
      for (int d = 8; d; d >>= 1) {
        unsigned long long o = __shfl_xor(mv, d, 16);
        if (o > mv) mv = o;
      }
      unsigned long long vwin = __shfl(mv, 0, 64);
      int idxWin = (int)(~(unsigned int)(vwin & 0xffffffffu)) & (Npts - 1);
      if (lane < 32)
        cf[lane] = supTb ? supTb[(size_t)idxWin * 32 + lane]
                         : sup_at(xyz, pf, b, lane, idxWin);
      if (lane == 0 && sb == 0) cidx[b * Mc + it + 1] = idxWin;
    }
    __syncthreads();
  }
}

// ---- K2 (runs last): new_xyz output, f32 ----
__global__ __launch_bounds__(256) void gather_kernel(
    const float* __restrict__ xyz, const int* __restrict__ cidx,
    float* __restrict__ oxyz, int out_size) {
  int idx = blockIdx.x * 256 + threadIdx.x;   // B*3*M = 12288
  if (idx >= out_size || idx >= 12288) return;
  int m = idx & (Mc - 1);
  int t = idx >> 10;          // b*3 + c
  int b = t / 3;
  int ci = cidx[b * Mc + m] & (Npts - 1);
  oxyz[idx] = sanf(xyz[(size_t)t * Npts + ci], 888.0f);
}

// ---- fallback ball (R15) ----
__global__ __launch_bounds__(256) void ball_kernel(
    const float* __restrict__ xyz, const float* __restrict__ pf,
    const int* __restrict__ cidx,
    unsigned short* __restrict__ idx0, int* __restrict__ cnt0,
    unsigned short* __restrict__ idx1, int* __restrict__ cnt1) {
  const int b = blockIdx.x >> 6;
  const int mt = blockIdx.x & 63;
  const int tid = threadIdx.x;
  __shared__ float cf[16][32];
  __shared__ float csq[16];
  __shared__ unsigned int ent[16][128];
  __shared__ int lcnt[16];
  for (int i = tid; i < 16 * 32; i += 256) {
    int ml = i >> 5, c = i & 31;
    int ci = cidx[b * Mc + mt * 16 + ml] & (Npts - 1);
    cf[ml][c] = sup_at(xyz, pf, b, c, ci);
  }
  if (tid < 16) lcnt[tid] = 0;
  __syncthreads();
  if (tid < 16) {
    float a = 0.f;
#pragma unroll
    for (int c = 0; c < 32; ++c) a = fmaf(cf[tid][c], cf[tid][c], a);
    csq[tid] = a;
  }
  __syncthreads();
  for (int ch = 0; ch < Npts / 256; ++ch) {
    int p = ch * 256 + tid;
    float x[32];
#pragma unroll
    for (int c = 0; c < 32; ++c) x[c] = sup_at(xyz, pf, b, c, p);
    float sp = 0.f;
#pragma unroll
    for (int c = 0; c < 32; ++c) sp = fmaf(x[c], x[c], sp);
#pragma unroll 4
    for (int ml = 0; ml < 16; ++ml) {
      float dot = 0.f;
#pragma unroll
      for (int c = 0; c < 32; ++c) dot = fmaf(cf[ml][c], x[c], dot);
      float d = sp - 2.0f * dot + csq[ml];
      if (d <= 0.04f) {
        int pos = atomicAdd(&lcnt[ml], 1);
        if (pos < 128) ent[ml][pos] = (unsigned int)p | (d <= 0.01f ? 0x80000000u : 0u);
      }
    }
  }
  __syncthreads();
  if (tid < 16) {
    int ml = tid;
    int nn = lcnt[ml]; if (nn > 128) nn = 128;
    for (int i = 1; i < nn; ++i) {
      unsigned int e = ent[ml][i]; unsigned int key = e & 0x7fffffffu;
      int j = i - 1;
      while (j >= 0 && (ent[ml][j] & 0x7fffffffu) > key) { ent[ml][j+1] = ent[ml][j]; --j; }
      ent[ml][j+1] = e;
    }
    int gm = b * Mc + mt * 16 + ml;
    int c1 = nn < 64 ? nn : 64;
    unsigned short first1 = nn > 0 ? (unsigned short)(ent[ml][0] & 0x7fffffffu) : 0;
    unsigned short* o1 = idx1 + (size_t)gm * 64;
    for (int j = 0; j < 64; ++j)
      o1[j] = j < c1 ? (unsigned short)(ent[ml][j] & 0x7fffffffu) : first1;
    cnt1[gm] = c1;
    unsigned short* o0 = idx0 + (size_t)gm * 32;
    int c0 = 0; unsigned short first0 = 0;
    for (int i = 0; i < nn && c0 < 32; ++i) {
      if (ent[ml][i] & 0x80000000u) {
        unsigned short nv = (unsigned short)(ent[ml][i] & 0x7fffffffu);
        if (c0 == 0) first0 = nv;
        o0[c0++] = nv;
      }
    }
    for (int j = c0; j < 32; ++j) o0[j] = first0;
    cnt0[gm] = c0;
  }
}

// ---- K4: attention, one wave per centroid. o = Wv @ (sum_j softmax_j * y_j). ----
template <int K>
__global__ __launch_bounds__(256) void attn_kernel(
    const float* __restrict__ xyz, const float* __restrict__ pf,
    const float* __restrict__ supT,            // may be null
    const int* __restrict__ cidx,
    const unsigned short* __restrict__ idxS, const int* __restrict__ cntS,
    const float* __restrict__ wq, const float* __restrict__ wk,
    const float* __restrict__ wv, const float* __restrict__ wo,
    __hip_bfloat16* __restrict__ outA) {
  __shared__ float WqL[64*33], WkL[64*33], WvL[64*33], WoL[32*65];  // +1 pad rows
  __shared__ float xv[4][32];
  __shared__ float qv[4][64];
  __shared__ float yb[4][2][32];
  __shared__ float ov[4][64];
  __shared__ int cns[4];
  const int tid = threadIdx.x;
  const int wid = tid >> 6, lane = tid & 63;
  const int gid = blockIdx.x;
  const int b = gid >> 8;
  const int m = ((gid & 255) << 2) + wid;
  const float* supTb = supT ? supT + (size_t)b * Npts * 32 : nullptr;
  for (int i = tid; i < 2048; i += 256) {
    int r = i >> 5, c = i & 31;
    WqL[r*33 + c] = wq[i];
    WkL[r*33 + c] = wk[i];
    WvL[r*33 + c] = wv[i];
    int ro = i >> 6, co = i & 63;
    WoL[ro*65 + co] = wo[i];
  }
  if (lane < 32) {
    int ci = cidx[b * Mc + m] & (Npts - 1);
    xv[wid][lane] = supTb ? supTb[(size_t)ci * 32 + lane]
                          : sup_at(xyz, pf, b, lane, ci);
  }
  if (lane == 0) cns[wid] = cntS[b * Mc + m];
  __syncthreads();
  {
    float acc = 0.f;
#pragma unroll
    for (int c = 0; c < 32; ++c) acc = fmaf(WqL[lane*33 + c], xv[wid][c], acc);
    qv[wid][lane] = acc;
  }
  __syncthreads();
  int cnt = cns[wid];
  cnt = cnt < 1 ? 1 : (cnt > K ? K : cnt);
  const int jj = lane < K ? lane : 0;
  int nj = (int)idxS[((size_t)b*Mc + m)*K + jj] & (Npts - 1);
  float y[32];
  if (supTb) {
    const float* yr = supTb + (size_t)nj * 32;
#pragma unroll
    for (int c = 0; c < 32; ++c) y[c] = yr[c] - xv[wid][c];
  } else {
#pragma unroll
    for (int c = 0; c < 32; ++c) y[c] = sup_at(xyz, pf, b, c, nj) - xv[wid][c];
  }
  float w0 = 0.f, w1 = 0.f;
#pragma unroll 2
  for (int r = 0; r < 32; ++r) {
    float k0 = 0.f, k1 = 0.f;
#pragma unroll
    for (int c = 0; c < 32; ++c) {
      k0 = fmaf(WkL[r*33 + c], y[c], k0);
      k1 = fmaf(WkL[(r+32)*33 + c], y[c], k1);
    }
    w0 = fmaf(qv[wid][r], k0, w0);
    w1 = fmaf(qv[wid][r+32], k1, w1);
  }
  const float iscale = 0.17677669529663689f;  // 1/sqrt(32)
  w0 *= iscale; w1 *= iscale;
  if (lane >= cnt) { w0 = -1e9f; w1 = -1e9f; }
  float mx0 = w0, mx1 = w1;
#pragma unroll
  for (int d = K/2; d; d >>= 1) {
    mx0 = fmaxf(mx0, __shfl_xor(mx0, d, K));
    mx1 = fmaxf(mx1, __shfl_xor(mx1, d, K));
  }
  float e0 = __expf(w0 - mx0), e1 = __expf(w1 - mx1);
  float s0 = e0, s1 = e1;
#pragma unroll
  for (int d = K/2; d; d >>= 1) {
    s0 += __shfl_xor(s0, d, K);
    s1 += __shfl_xor(s1, d, K);
  }
  float wn0 = e0 / s0, wn1 = e1 / s1;
#pragma unroll
  for (int c = 0; c < 32; ++c) {
    float t0 = wn0 * y[c], t1 = wn1 * y[c];
#pragma unroll
    for (int d = K/2; d; d >>= 1) {
      t0 += __shfl_xor(t0, d, K);
      t1 += __shfl_xor(t1, d, K);
    }
    if (lane == 0) { yb[wid][0][c] = t0; yb[wid][1][c] = t1; }
  }
  __syncthreads();
  {
    const int h = lane >> 5;
    float a2 = 0.f;
#pragma unroll
    for (int c = 0; c < 32; ++c) a2 = fmaf(WvL[lane*33 + c], yb[wid][h][c], a2);
    ov[wid][lane] = a2;
  }
  __syncthreads();
  if (lane < 32) {
    float a3 = 0.f;
#pragma unroll
    for (int r = 0; r < 64; ++r) a3 = fmaf(WoL[lane*65 + r], ov[wid][r], a3);
    outA[((size_t)b*32 + lane)*Mc + m] = __float2bfloat16(a3 + xv[wid][lane]);
  }
}

// ---- K5: conv0 (64x32) + bias, BN stats via atomics ----
__global__ __launch_bounds__(256) void conv0_kernel(
    const __hip_bfloat16* __restrict__ inA, const float* __restrict__ w0,
    const float* __restrict__ b0, __hip_bfloat16* __restrict__ z0,
    float* __restrict__ ssum, float* __restrict__ ssq) {
  int idx = blockIdx.x * 256 + threadIdx.x;   // B*64*M
  int m = idx & (Mc - 1);
  int r = (idx >> 10) & 63;
  int b = idx >> 16;
  float acc = b0[r];
#pragma unroll
  for (int c = 0; c < 32; ++c)
    acc = fmaf(w0[r*32 + c], __bfloat162float(inA[((size_t)b*32 + c)*Mc + m]), acc);
  z0[((size_t)b*64 + r)*Mc + m] = __float2bfloat16(acc);
  float s = acc, q = acc * acc;
#pragma unroll
  for (int d = 32; d; d >>= 1) { s += __shfl_down(s, d, 64); q += __shfl_down(q, d, 64); }
  if ((threadIdx.x & 63) == 0) { atomicAdd(&ssum[r], s); atomicAdd(&ssq[r], q); }
}

// ---- K6: conv1 stats pass (folds bnfin0); optionally stores z1 f32 ----
__global__ __launch_bounds__(256) void conv1_stats_kernel(
    const __hip_bfloat16* __restrict__ z0,
    const float* __restrict__ ssum0, const float* __restrict__ ssq0,
    const float* __restrict__ g0, const float* __restrict__ t0,
    const float* __restrict__ w1, const float* __restrict__ b1,
    float* __restrict__ z1,                       // may be null
    float* __restrict__ ssum1, float* __restrict__ ssq1) {
  __shared__ float A0s[64], B0s[64];
  int tid = threadIdx.x;
  if (tid < 64) {
    float mu = ssum0[tid] * (1.0f/4096.0f);
    float var = ssq0[tid] * (1.0f/4096.0f) - mu * mu;
    if (var < 0.f) var = 0.f;
    float a = g0[tid] * rsqrtf(var + BN_EPS);
    A0s[tid] = a;
    B0s[tid] = t0[tid] - mu * a;
  }
  __syncthreads();
  int idx = blockIdx.x * 256 + tid;   // B*128*M
  int m = idx & (Mc - 1);
  int r2 = (idx >> 10) & 127;
  int b = idx >> 17;
  float acc = b1[r2];
#pragma unroll 8
  for (int r = 0; r < 64; ++r) {
    float u = fmaf(__bfloat162float(z0[((size_t)b*64 + r)*Mc + m]), A0s[r], B0s[r]);
    u = u > 0.f ? u : SLOPE * u;
    acc = fmaf(w1[r2*64 + r], u, acc);
  }
  if (z1) z1[idx] = acc;
  float s = acc, q = acc * acc;
#pragma unroll
  for (int d = 32; d; d >>= 1) { s += __shfl_down(s, d, 64); q += __shfl_down(q, d, 64); }
  if ((tid & 63) == 0) { atomicAdd(&ssum1[r2], s); atomicAdd(&ssq1[r2], q); }
}

// ---- K7: conv1 write pass (folds bnfin0+bnfin1); z1 path or recompute ----
__global__ __launch_bounds__(256) void conv1_write_kernel(
    const __hip_bfloat16* __restrict__ z0, const float* __restrict__ z1,
    const float* __restrict__ ssum0, const float* __restrict__ ssq0,
    const float* __restrict__ g0, const float* __restrict__ t0,
    const float* __restrict__ w1, const float* __restrict__ b1,
    const float* __restrict__ ssum1, const float* __restrict__ ssq1,
    const float* __restrict__ g1, const float* __restrict__ t1,
    float* __restrict__ outAll, int chOff, int out_size) {
  __shared__ float A0s[64], B0s[64];
  __shared__ float ab1[2];
  int tid = threadIdx.x;
  int idx = blockIdx.x * 256 + tid;   // B*128*M
  int m = idx & (Mc - 1);
  int r2 = (idx >> 10) & 127;         // uniform within block (256 | 1024)
  int b = idx >> 17;
  if (!z1 && tid < 64) {
    float mu = ssum0[tid] * (1.0f/4096.0f);
    float var = ssq0[tid] * (1.0f/4096.0f) - mu * mu;
    if (var < 0.f) var = 0.f;
    float a = g0[tid] * rsqrtf(var + BN_EPS);
    A0s[tid] = a;
    B0s[tid] = t0[tid] - mu * a;
  }
  if (tid == 0) {
    float mu = ssum1[r2] * (1.0f/4096.0f);
    float var = ssq1[r2] * (1.0f/4096.0f) - mu * mu;
    if (var < 0.f) var = 0.f;
    float a = g1[r2] * rsqrtf(var + BN_EPS);
    ab1[0] = a;
    ab1[1] = t1[r2] - mu * a;
  }
  __syncthreads();
  float acc;
  if (z1) {
    acc = z1[idx];
  } else {
    acc = b1[r2];
#pragma unroll 8
    for (int r = 0; r < 64; ++r) {
      float u = fmaf(__bfloat162float(z0[((size_t)b*64 + r)*Mc + m]), A0s[r], B0s[r]);
      u = u > 0.f ? u : SLOPE * u;
      acc = fmaf(w1[r2*64 + r], u, acc);
    }
  }
  float v = fmaf(acc, ab1[0], ab1[1]);
  size_t oidx = 12288 + ((size_t)b*256 + chOff + r2)*Mc + m;
  if (oidx < (size_t)out_size) outAll[oidx] = sanf(v, 777.0f);
}

extern "C" void kernel_launch(void* const* d_in, const int* in_sizes, int n_in,
                              void* d_out, int out_size, void* d_ws, size_t ws_size,
                              hipStream_t stream) {
  float* outb = (float*)d_out;
  int fillBlocks = (out_size + 255) / 256;
  if (n_in != 26 || in_sizes[0] != Bb*3*Npts || in_sizes[1] != Bb*29*Npts
      || in_sizes[2] != 2048) {
    fill_kernel<<<fillBlocks, 256, 0, stream>>>(outb, out_size, 7777.0f);
    return;
  }
  if (out_size != OUT_EXPECT) {
    fill_kernel<<<fillBlocks, 256, 0, stream>>>(outb, out_size, 23456.0f);
    return;
  }
  if (ws_size < WS_REQUIRED) {
    fill_kernel<<<fillBlocks, 256, 0, stream>>>(outb, out_size, 12345.0f);
    return;
  }
  const float* xyz = (const float*)d_in[0];
  const float* pf  = (const float*)d_in[1];
  char* ws = (char*)d_ws;
  int* cidx = (int*)(ws + OFF_CIDX);
  unsigned short* idx0 = (unsigned short*)(ws + OFF_IDX0);
  int* cnt0 = (int*)(ws + OFF_CNT0);
  unsigned short* idx1 = (unsigned short*)(ws + OFF_IDX1);
  int* cnt1 = (int*)(ws + OFF_CNT1);
  unsigned long long* fslots = (unsigned long long*)(ws + OFF_FSLOT);
  __hip_bfloat16* attn = (__hip_bfloat16*)(ws + OFF_ATTN);
  __hip_bfloat16* z0 = (__hip_bfloat16*)(ws + OFF_Z0);
  const bool fused = (ws_size >= WS_T_REQUIRED);
  float* z1 = (ws_size >= WS_Z1_REQUIRED) ? (float*)(ws + OFF_Z1) : nullptr;
  float* supT = fused ? (float*)(ws + OFF_SUPT) : nullptr;
  unsigned int* gcnt = (unsigned int*)(ws + OFF_GCNT);
  unsigned int* gent = (unsigned int*)(ws + OFF_GENT);

  hipMemsetAsync(ws, 0, ZERO_BYTES, stream);                 // stats + gcnt
  hipMemsetAsync(ws + OFF_FSLOT, 0, FSLOT_BYTES, stream);    // fps val slots
  if (fused) {
    hipMemsetAsync(ws + OFF_CIDX, 0xFF, Bb * Mc * 4, stream); // cidx sentinels
    buildT_kernel<<<Bb*Npts/256, 256, 0, stream>>>(xyz, pf, supT);
    fps_ball_kernel<<<192, 512, 0, stream>>>(xyz, pf, supT, (unsigned int*)cidx,
                                             fslots, gcnt, gent);
    ballpost_kernel<<<16, 256, 0, stream>>>(gcnt, gent, idx0, cnt0, idx1, cnt1);
  } else {
    fps_kernel<<<Bb*NBLK, 512, 0, stream>>>(xyz, pf, supT, cidx, fslots);
    ball_kernel<<<Bb*64, 256, 0, stream>>>(xyz, pf, cidx, idx0, cnt0, idx1, cnt1);
  }

  for (int s = 0; s < 2; ++s) {
    const float* aq = (const float*)d_in[2 + s*12 + 0];
    const float* ak = (const float*)d_in[2 + s*12 + 1];
    const float* av = (const float*)d_in[2 + s*12 + 2];
    const float* ao = (const float*)d_in[2 + s*12 + 3];
    const float* w0 = (const float*)d_in[2 + s*12 + 4];
    const float* b0 = (const float*)d_in[2 + s*12 + 5];
    const float* g0 = (const float*)d_in[2 + s*12 + 6];
    const float* t0 = (const float*)d_in[2 + s*12 + 7];
    const float* w1 = (const float*)d_in[2 + s*12 + 8];
    const float* b1 = (const float*)d_in[2 + s*12 + 9];
    const float* g1 = (const float*)d_in[2 + s*12 + 10];
    const float* t1 = (const float*)d_in[2 + s*12 + 11];
    float* st = (float*)(ws + OFF_STATS) + (size_t)s*384;
    float *sum0 = st, *sq0 = st + 64, *sum1 = st + 128, *sq1 = st + 256;
    if (s == 0)
      attn_kernel<32><<<Bb*Mc/4, 256, 0, stream>>>(xyz, pf, supT, cidx, idx0, cnt0,
                                                   aq, ak, av, ao, attn);
    else
      attn_kernel<64><<<Bb*Mc/4, 256, 0, stream>>>(xyz, pf, supT, cidx, idx1, cnt1,
                                                   aq, ak, av, ao, attn);
    conv0_kernel<<<Bb*64*Mc/256, 256, 0, stream>>>(attn, w0, b0, z0, sum0, sq0);
    conv1_stats_kernel<<<Bb*128*Mc/256, 256, 0, stream>>>(z0, sum0, sq0, g0, t0,
                                                          w1, b1, z1, sum1, sq1);
    conv1_write_kernel<<<Bb*128*Mc/256, 256, 0, stream>>>(z0, z1, sum0, sq0, g0, t0,
                                                          w1, b1, sum1, sq1, g1, t1,
                                                          outb, s*128, out_size);
  }
  gather_kernel<<<48, 256, 0, stream>>>(xyz, cidx, outb, out_size);
}

// Round 17
// 2607.850 us; speedup vs baseline: 1.3807x; 1.0311x over previous
//
#include <hip/hip_runtime.h>
#include <hip/hip_bf16.h>

// PointNetMSG on MI355X. Inputs FP32, output FP32. Internal fp32.
// B=4, N=16384, Cs=32, M=1024, scales: (r=0.1,k=32),(r=0.2,k=64).
// R17: (1) fps_ball consumer poll damping s_sleep(2)->(16) — less LLC poll
// traffic perturbing the fps rendezvous (the +140us R16 delta). (2) tail:
// both scales merged into single attn/conv0/conv1 launches (gated on
// ws >= 15.06MB; R16 sequential-scale tail as fallback).

static constexpr int Bb = 4;
static constexpr int Npts = 16384;
static constexpr int Mc = 1024;
static constexpr int NBLK = 16;
static constexpr int OUT_EXPECT = 12288 + 1048576;
#define BN_EPS 1e-5f
#define SLOPE 0.02f
#define SCOPE_AGT __HIP_MEMORY_SCOPE_AGENT

// ---- workspace layout ----
static constexpr size_t OFF_STATS = 33024;    // f32 [2][384]
static constexpr size_t OFF_GCNT  = 40960;    // u32 [4][1024] (zeroed)
static constexpr size_t ZERO_BYTES = 65536;
static constexpr size_t OFF_CIDX  = 65536;    // u32 [4][1024] (memset 0xFF in fused path)
static constexpr size_t OFF_IDX0  = 81920;    // u16 [4][1024][32]
static constexpr size_t OFF_CNT0  = 344064;   // i32 [4][1024]
static constexpr size_t OFF_IDX1  = 360448;   // u16 [4][1024][64]
static constexpr size_t OFF_CNT1  = 884736;   // i32 [4][1024]
static constexpr size_t OFF_ATTN  = 901120;   // bf16 [4][32][1024]  (scale0)
static constexpr size_t OFF_Z0    = 1163264;  // bf16 [4][64][1024]  (scale0)
static constexpr size_t WS_REQUIRED = 1687552;
// fps val slots u64[4][1024][16] = 512 KB, aliased over attn/z0 (fps-only lifetime)
static constexpr size_t OFF_FSLOT = 901120;
static constexpr size_t FSLOT_BYTES = (size_t)Bb * Mc * NBLK * 8;
// z1 scale0 f32 = 2 MB; aliased by gent u32[4][1024][128] (ballpost consumes first)
static constexpr size_t OFF_Z1 = 1687552;
static constexpr size_t OFF_GENT = OFF_Z1;
static constexpr size_t WS_Z1_REQUIRED = OFF_Z1 + (size_t)Bb * 128 * Mc * 4;
// point-major mirror f32 [4][16384][32] = 8 MB (proven active R15/R16)
static constexpr size_t OFF_SUPT = WS_Z1_REQUIRED;
static constexpr size_t WS_T_REQUIRED = OFF_SUPT + (size_t)Bb * Npts * 32 * 4;
// combined-tail extension: attn1 bf16 256KB + z01 bf16 512KB + z11 f32 2MB
static constexpr size_t OFF_ATTN1 = WS_T_REQUIRED;
static constexpr size_t OFF_Z01   = OFF_ATTN1 + (size_t)Bb * 32 * Mc * 2;
static constexpr size_t OFF_Z11   = OFF_Z01 + (size_t)Bb * 64 * Mc * 2;
static constexpr size_t WS_EXT_REQUIRED = OFF_Z11 + (size_t)Bb * 128 * Mc * 4;

__device__ __forceinline__ float sup_at(const float* xyz, const float* pf,
                                        int b, int c, int n) {
  return (c < 3) ? xyz[((size_t)b*3 + c)*Npts + n]
                 : pf[((size_t)b*29 + (c-3))*Npts + n];
}

__device__ __forceinline__ float sanf(float v, float repl) {
  if (!(v == v) || fabsf(v) > 1e30f) v = repl;
  return v;
}

__global__ __launch_bounds__(256) void fill_kernel(float* out, int n, float val) {
  int i = blockIdx.x * 256 + threadIdx.x;
  if (i < n) out[i] = val;
}

// ---- K0: build point-major mirror supT[b][n][32] ----
__global__ __launch_bounds__(256) void buildT_kernel(
    const float* __restrict__ xyz, const float* __restrict__ pf,
    float* __restrict__ supT) {
  int idx = blockIdx.x * 256 + threadIdx.x;
  int n = idx & (Npts - 1);
  int b = idx >> 14;
  float* dst = supT + ((size_t)b * Npts + n) * 32;
#pragma unroll
  for (int c = 0; c < 32; ++c) dst[c] = sup_at(xyz, pf, b, c, n);
}

// ---- K1 (merged): 64 fps producers + 128 ballpoint consumers ----
__global__ __launch_bounds__(512, 2) void fps_ball_kernel(
    const float* __restrict__ xyz, const float* __restrict__ pf,
    const float* __restrict__ supT,
    unsigned int* __restrict__ cidx, unsigned long long* __restrict__ slots,
    unsigned int* __restrict__ gcnt, unsigned int* __restrict__ gent) {
  const int tid = threadIdx.x;
  if (blockIdx.x < 64) {
    const int blk = blockIdx.x;
    const int b = blk >> 4;
    const int sb = blk & (NBLK - 1);
    const int lane = tid & 63, wid = tid >> 6;
    float f0[32], f1[32];
    const int p0 = sb * 1024 + tid;
    const int p1 = p0 + 512;
    float d0 = 1e10f, d1 = 1e10f;
#pragma unroll
    for (int c = 0; c < 32; ++c) {
      f0[c] = sup_at(xyz, pf, b, c, p0);
      f1[c] = sup_at(xyz, pf, b, c, p1);
    }
    __shared__ float cf[32];
    __shared__ unsigned long long red[8];
    if (sb == 0 && tid == 0) atomicExch(&cidx[b * Mc], 0u);
    if (tid < 32) cf[tid] = sup_at(xyz, pf, b, tid, 0);
    __syncthreads();
    unsigned long long* slotb = slots + (size_t)b * Mc * NBLK;
    const float* supTb = supT + (size_t)b * Npts * 32;
    for (int it = 0; it < Mc - 1; ++it) {
      float cc[32];
#pragma unroll
      for (int c = 0; c < 32; ++c) cc[c] = cf[c];
      {
        float d = 0.f, e = 0.f;
#pragma unroll
        for (int c = 0; c < 32; ++c) {
          float t0 = f0[c] - cc[c];
          float s0 = __fmul_rn(t0, t0);
          d = (c == 0) ? s0 : __fadd_rn(d, s0);
          float t1 = f1[c] - cc[c];
          float s1 = __fmul_rn(t1, t1);
          e = (c == 0) ? s1 : __fadd_rn(e, s1);
        }
        d0 = fminf(d0, d);
        d1 = fminf(d1, e);
      }
      float bd; int bp;
      if (d0 >= d1) { bd = d0; bp = p0; } else { bd = d1; bp = p1; }
      unsigned long long v =
          ((unsigned long long)__float_as_uint(bd) << 32) | (unsigned int)(~(unsigned int)bp);
#pragma unroll
      for (int d = 32; d; d >>= 1) {
        unsigned long long o = __shfl_xor(v, d, 64);
        if (o > v) v = o;
      }
      if (lane == 0) red[wid] = v;
      __syncthreads();
      if (tid == 0) {
        unsigned long long vb = red[0];
#pragma unroll
        for (int w = 1; w < 8; ++w) if (red[w] > vb) vb = red[w];
        atomicMax(&slotb[(size_t)it * NBLK + sb], vb);
      }
      if (wid == 0) {
        unsigned long long myv = 0;
        if (lane < NBLK) {
          const unsigned long long* sp = &slotb[(size_t)it * NBLK + lane];
          while ((myv = __hip_atomic_load(sp, __ATOMIC_RELAXED, SCOPE_AGT)) == 0ull)
            __builtin_amdgcn_s_sleep(1);
        }
        unsigned long long mv = myv;
#pragma unroll
        for (int d = 8; d; d >>= 1) {
          unsigned long long o = __shfl_xor(mv, d, 16);
          if (o > mv) mv = o;
        }
        unsigned long long vwin = __shfl(mv, 0, 64);
        int idxWin = (int)(~(unsigned int)(vwin & 0xffffffffu)) & (Npts - 1);
        if (lane < 32) cf[lane] = supTb[(size_t)idxWin * 32 + lane];
        if (lane == 0 && sb == 0)
          atomicExch(&cidx[b * Mc + it + 1], (unsigned int)idxWin);
      }
      __syncthreads();
    }
  } else {
    const int blk2 = blockIdx.x - 64;
    const int b = blk2 >> 5;
    const int chunk = blk2 & 31;
    const int p = chunk * 512 + tid;
    const float* supTb = supT + (size_t)b * Npts * 32;
    float x[32];
    const float* srow = supTb + (size_t)p * 32;
#pragma unroll
    for (int c = 0; c < 32; ++c) x[c] = srow[c];
    float sp = 0.f;
#pragma unroll
    for (int c = 0; c < 32; ++c) sp = fmaf(x[c], x[c], sp);
    __shared__ float cfb[2][32];
    unsigned int* cidxb = cidx + b * Mc;
    unsigned int* gcntb = gcnt + b * Mc;
    unsigned int* gentb = gent + (size_t)b * Mc * 128;
    for (int m = 0; m < Mc; ++m) {
      if (tid < 32) {
        unsigned int ci;
        const unsigned int* cp = &cidxb[m];
        while ((ci = __hip_atomic_load(cp, __ATOMIC_RELAXED, SCOPE_AGT)) == 0xFFFFFFFFu)
          __builtin_amdgcn_s_sleep(16);    // R17: damped poll (was 2)
        cfb[m & 1][tid] = supTb[(size_t)(ci & (Npts - 1)) * 32 + tid];
      }
      __syncthreads();
      const float* cfm = cfb[m & 1];
      float csq = 0.f, dot = 0.f;
#pragma unroll
      for (int c = 0; c < 32; ++c) {
        csq = fmaf(cfm[c], cfm[c], csq);
        dot = fmaf(cfm[c], x[c], dot);
      }
      float d = sp - 2.0f * dot + csq;
      if (d <= 0.04f) {
        int pos = atomicAdd(&gcntb[m], 1u);
        if (pos < 128)
          gentb[(size_t)m * 128 + pos] = (unsigned int)p | (d <= 0.01f ? 0x80000000u : 0u);
      }
    }
  }
}

// ---- K1b: ballpost ----
__global__ __launch_bounds__(256) void ballpost_kernel(
    unsigned int* __restrict__ gcnt, unsigned int* __restrict__ gent,
    unsigned short* __restrict__ idx0, int* __restrict__ cnt0,
    unsigned short* __restrict__ idx1, int* __restrict__ cnt1) {
  int idx = blockIdx.x * 256 + threadIdx.x;
  int b = idx >> 10;
  int m = idx & (Mc - 1);
  int gm = b * Mc + m;
  unsigned int* e = gent + (size_t)gm * 128;
  int nn = (int)gcnt[gm]; if (nn > 128) nn = 128;
  for (int i = 1; i < nn; ++i) {
    unsigned int ei = e[i]; unsigned int key = ei & 0x7fffffffu;
    int j = i - 1;
    while (j >= 0 && (e[j] & 0x7fffffffu) > key) { e[j+1] = e[j]; --j; }
    e[j+1] = ei;
  }
  int c1 = nn < 64 ? nn : 64;
  unsigned short first1 = nn > 0 ? (unsigned short)(e[0] & 0x7fffffffu) : 0;
  unsigned short* o1 = idx1 + (size_t)gm * 64;
  for (int j = 0; j < 64; ++j)
    o1[j] = j < c1 ? (unsigned short)(e[j] & 0x7fffffffu) : first1;
  cnt1[gm] = c1;
  unsigned short* o0 = idx0 + (size_t)gm * 32;
  int c0 = 0; unsigned short first0 = 0;
  for (int i = 0; i < nn && c0 < 32; ++i) {
    if (e[i] & 0x80000000u) {
      unsigned short nv = (unsigned short)(e[i] & 0x7fffffffu);
      if (c0 == 0) first0 = nv;
      o0[c0++] = nv;
    }
  }
  for (int j = c0; j < 32; ++j) o0[j] = first0;
  cnt0[gm] = c0;
}

// ---- fallback fps (R15) ----
__global__ __launch_bounds__(512, 2) void fps_kernel(
    const float* __restrict__ xyz, const float* __restrict__ pf,
    const float* __restrict__ supT,
    int* __restrict__ cidx, unsigned long long* __restrict__ slots) {
  const int blk = blockIdx.x;
  const int b = blk >> 4;
  const int sb = blk & (NBLK - 1);
  const int tid = threadIdx.x;
  const int lane = tid & 63, wid = tid >> 6;
  float f0[32], f1[32];
  const int p0 = sb * 1024 + tid;
  const int p1 = p0 + 512;
  float d0 = 1e10f, d1 = 1e10f;
#pragma unroll
  for (int c = 0; c < 32; ++c) {
    f0[c] = sup_at(xyz, pf, b, c, p0);
    f1[c] = sup_at(xyz, pf, b, c, p1);
  }
  __shared__ float cf[32];
  __shared__ unsigned long long red[8];
  if (sb == 0 && tid == 0) cidx[b * Mc] = 0;
  if (tid < 32) cf[tid] = sup_at(xyz, pf, b, tid, 0);
  __syncthreads();
  unsigned long long* slotb = slots + (size_t)b * Mc * NBLK;
  const float* supTb = supT ? supT + (size_t)b * Npts * 32 : nullptr;
  for (int it = 0; it < Mc - 1; ++it) {
    float cc[32];
#pragma unroll
    for (int c = 0; c < 32; ++c) cc[c] = cf[c];
    {
      float d = 0.f, e = 0.f;
#pragma unroll
      for (int c = 0; c < 32; ++c) {
        float t0 = f0[c] - cc[c];
        float s0 = __fmul_rn(t0, t0);
        d = (c == 0) ? s0 : __fadd_rn(d, s0);
        float t1 = f1[c] - cc[c];
        float s1 = __fmul_rn(t1, t1);
        e = (c == 0) ? s1 : __fadd_rn(e, s1);
      }
      d0 = fminf(d0, d);
      d1 = fminf(d1, e);
    }
    float bd; int bp;
    if (d0 >= d1) { bd = d0; bp = p0; } else { bd = d1; bp = p1; }
    unsigned long long v =
        ((unsigned long long)__float_as_uint(bd) << 32) | (unsigned int)(~(unsigned int)bp);
#pragma unroll
    for (int d = 32; d; d >>= 1) {
      unsigned long long o = __shfl_xor(v, d, 64);
      if (o > v) v = o;
    }
    if (lane == 0) red[wid] = v;
    __syncthreads();
    if (tid == 0) {
      unsigned long long vb = red[0];
#pragma unroll
      for (int w = 1; w < 8; ++w) if (red[w] > vb) vb = red[w];
      atomicMax(&slotb[(size_t)it * NBLK + sb], vb);
    }
    if (wid == 0) {
      unsigned long long myv = 0;
      if (lane < NBLK) {
        const unsigned long long* sp = &slotb[(size_t)it * NBLK + lane];
        while ((myv = __hip_atomic_load(sp, __ATOMIC_RELAXED, SCOPE_AGT)) == 0ull)
          __builtin_amdgcn_s_sleep(1);
      }
      unsigned long long mv = myv;
#pragma unroll
      for (int d = 8; d; d >>= 1) {
        unsigned long long o = __shfl_xor(mv, d, 16);
        if (o > mv) mv = o;
      }
      unsigned long long vwin = __shfl(mv, 0, 64);
      int idxWin = (int)(~(unsigned int)(vwin & 0xffffffffu)) & (Npts - 1);
      if (lane < 32)
        cf[lane] = supTb ? supTb[(size_t)idxWin * 32 + lane]
                         : sup_at(xyz, pf, b, lane, idxWin);
      if (lane == 0 && sb == 0) cidx[b * Mc + it + 1] = idxWin;
    }
    __syncthreads();
  }
}

// ---- K2 (runs last): new_xyz output ----
__global__ __launch_bounds__(256) void gather_kernel(
    const float* __restrict__ xyz, const int* __restrict__ cidx,
    float* __restrict__ oxyz, int out_size) {
  int idx = blockIdx.x * 256 + threadIdx.x;
  if (idx >= out_size || idx >= 12288) return;
  int m = idx & (Mc - 1);
  int t = idx >> 10;
  int b = t / 3;
  int ci = cidx[b * Mc + m] & (Npts - 1);
  oxyz[idx] = sanf(xyz[(size_t)t * Npts + ci], 888.0f);
}

// ---- fallback ball (R15) ----
__global__ __launch_bounds__(256) void ball_kernel(
    const float* __restrict__ xyz, const float* __restrict__ pf,
    const int* __restrict__ cidx,
    unsigned short* __restrict__ idx0, int* __restrict__ cnt0,
    unsigned short* __restrict__ idx1, int* __restrict__ cnt1) {
  const int b = blockIdx.x >> 6;
  const int mt = blockIdx.x & 63;
  const int tid = threadIdx.x;
  __shared__ float cf[16][32];
  __shared__ float csq[16];
  __shared__ unsigned int ent[16][128];
  __shared__ int lcnt[16];
  for (int i = tid; i < 16 * 32; i += 256) {
    int ml = i >> 5, c = i & 31;
    int ci = cidx[b * Mc + mt * 16 + ml] & (Npts - 1);
    cf[ml][c] = sup_at(xyz, pf, b, c, ci);
  }
  if (tid < 16) lcnt[tid] = 0;
  __syncthreads();
  if (tid < 16) {
    float a = 0.f;
#pragma unroll
    for (int c = 0; c < 32; ++c) a = fmaf(cf[tid][c], cf[tid][c], a);
    csq[tid] = a;
  }
  __syncthreads();
  for (int ch = 0; ch < Npts / 256; ++ch) {
    int p = ch * 256 + tid;
    float x[32];
#pragma unroll
    for (int c = 0; c < 32; ++c) x[c] = sup_at(xyz, pf, b, c, p);
    float sp = 0.f;
#pragma unroll
    for (int c = 0; c < 32; ++c) sp = fmaf(x[c], x[c], sp);
#pragma unroll 4
    for (int ml = 0; ml < 16; ++ml) {
      float dot = 0.f;
#pragma unroll
      for (int c = 0; c < 32; ++c) dot = fmaf(cf[ml][c], x[c], dot);
      float d = sp - 2.0f * dot + csq[ml];
      if (d <= 0.04f) {
        int pos = atomicAdd(&lcnt[ml], 1);
        if (pos < 128) ent[ml][pos] = (unsigned int)p | (d <= 0.01f ? 0x80000000u : 0u);
      }
    }
  }
  __syncthreads();
  if (tid < 16) {
    int ml = tid;
    int nn = lcnt[ml]; if (nn > 128) nn = 128;
    for (int i = 1; i < nn; ++i) {
      unsigned int e = ent[ml][i]; unsigned int key = e & 0x7fffffffu;
      int j = i - 1;
      while (j >= 0 && (ent[ml][j] & 0x7fffffffu) > key) { ent[ml][j+1] = ent[ml][j]; --j; }
      ent[ml][j+1] = e;
    }
    int gm = b * Mc + mt * 16 + ml;
    int c1 = nn < 64 ? nn : 64;
    unsigned short first1 = nn > 0 ? (unsigned short)(ent[ml][0] & 0x7fffffffu) : 0;
    unsigned short* o1 = idx1 + (size_t)gm * 64;
    for (int j = 0; j < 64; ++j)
      o1[j] = j < c1 ? (unsigned short)(ent[ml][j] & 0x7fffffffu) : first1;
    cnt1[gm] = c1;
    unsigned short* o0 = idx0 + (size_t)gm * 32;
    int c0 = 0; unsigned short first0 = 0;
    for (int i = 0; i < nn && c0 < 32; ++i) {
      if (ent[ml][i] & 0x80000000u) {
        unsigned short nv = (unsigned short)(ent[ml][i] & 0x7fffffffu);
        if (c0 == 0) first0 = nv;
        o0[c0++] = nv;
      }
    }
    for (int j = c0; j < 32; ++j) o0[j] = first0;
    cnt0[gm] = c0;
  }
}

// ---- attention body (device), one wave per centroid ----
template <int K>
__device__ __forceinline__ void attn_body(
    const float* xyz, const float* pf, const float* supTb,
    const int* cidx, const unsigned short* idxS, const int* cntS,
    const float* wq, const float* wk, const float* wv, const float* wo,
    __hip_bfloat16* outA, int b, int m, int wid, int lane, int tid,
    float* WqL, float* WkL, float* WvL, float* WoL,
    float (*xv)[32], float (*qv)[64], float (*yb)[2][32], float (*ov)[64], int* cns) {
  for (int i = tid; i < 2048; i += 256) {
    int r = i >> 5, c = i & 31;
    WqL[r*33 + c] = wq[i];
    WkL[r*33 + c] = wk[i];
    WvL[r*33 + c] = wv[i];
    int ro = i >> 6, co = i & 63;
    WoL[ro*65 + co] = wo[i];
  }
  if (lane < 32) {
    int ci = cidx[b * Mc + m] & (Npts - 1);
    xv[wid][lane] = supTb ? supTb[(size_t)ci * 32 + lane]
                          : sup_at(xyz, pf, b, lane, ci);
  }
  if (lane == 0) cns[wid] = cntS[b * Mc + m];
  __syncthreads();
  {
    float acc = 0.f;
#pragma unroll
    for (int c = 0; c < 32; ++c) acc = fmaf(WqL[lane*33 + c], xv[wid][c], acc);
    qv[wid][lane] = acc;
  }
  __syncthreads();
  int cnt = cns[wid];
  cnt = cnt < 1 ? 1 : (cnt > K ? K : cnt);
  const int jj = lane < K ? lane : 0;
  int nj = (int)idxS[((size_t)b*Mc + m)*K + jj] & (Npts - 1);
  float y[32];
  if (supTb) {
    const float* yr = supTb + (size_t)nj * 32;
#pragma unroll
    for (int c = 0; c < 32; ++c) y[c] = yr[c] - xv[wid][c];
  } else {
#pragma unroll
    for (int c = 0; c < 32; ++c) y[c] = sup_at(xyz, pf, b, c, nj) - xv[wid][c];
  }
  float w0 = 0.f, w1 = 0.f;
#pragma unroll 2
  for (int r = 0; r < 32; ++r) {
    float k0 = 0.f, k1 = 0.f;
#pragma unroll
    for (int c = 0; c < 32; ++c) {
      k0 = fmaf(WkL[r*33 + c], y[c], k0);
      k1 = fmaf(WkL[(r+32)*33 + c], y[c], k1);
    }
    w0 = fmaf(qv[wid][r], k0, w0);
    w1 = fmaf(qv[wid][r+32], k1, w1);
  }
  const float iscale = 0.17677669529663689f;
  w0 *= iscale; w1 *= iscale;
  if (lane >= cnt) { w0 = -1e9f; w1 = -1e9f; }
  float mx0 = w0, mx1 = w1;
#pragma unroll
  for (int d = K/2; d; d >>= 1) {
    mx0 = fmaxf(mx0, __shfl_xor(mx0, d, K));
    mx1 = fmaxf(mx1, __shfl_xor(mx1, d, K));
  }
  float e0 = __expf(w0 - mx0), e1 = __expf(w1 - mx1);
  float s0 = e0, s1 = e1;
#pragma unroll
  for (int d = K/2; d; d >>= 1) {
    s0 += __shfl_xor(s0, d, K);
    s1 += __shfl_xor(s1, d, K);
  }
  float wn0 = e0 / s0, wn1 = e1 / s1;
#pragma unroll
  for (int c = 0; c < 32; ++c) {
    float t0 = wn0 * y[c], t1 = wn1 * y[c];
#pragma unroll
    for (int d = K/2; d; d >>= 1) {
      t0 += __shfl_xor(t0, d, K);
      t1 += __shfl_xor(t1, d, K);
    }
    if (lane == 0) { yb[wid][0][c] = t0; yb[wid][1][c] = t1; }
  }
  __syncthreads();
  {
    const int h = lane >> 5;
    float a2 = 0.f;
#pragma unroll
    for (int c = 0; c < 32; ++c) a2 = fmaf(WvL[lane*33 + c], yb[wid][h][c], a2);
    ov[wid][lane] = a2;
  }
  __syncthreads();
  if (lane < 32) {
    float a3 = 0.f;
#pragma unroll
    for (int r = 0; r < 64; ++r) a3 = fmaf(WoL[lane*65 + r], ov[wid][r], a3);
    outA[((size_t)b*32 + lane)*Mc + m] = __float2bfloat16(a3 + xv[wid][lane]);
  }
}

// ---- K4a: per-scale attn (fallback path) ----
template <int K>
__global__ __launch_bounds__(256) void attn_kernel(
    const float* __restrict__ xyz, const float* __restrict__ pf,
    const float* __restrict__ supT, const int* __restrict__ cidx,
    const unsigned short* __restrict__ idxS, const int* __restrict__ cntS,
    const float* __restrict__ wq, const float* __restrict__ wk,
    const float* __restrict__ wv, const float* __restrict__ wo,
    __hip_bfloat16* __restrict__ outA) {
  __shared__ float WqL[64*33], WkL[64*33], WvL[64*33], WoL[32*65];
  __shared__ float xv[4][32];
  __shared__ float qv[4][64];
  __shared__ float yb[4][2][32];
  __shared__ float ov[4][64];
  __shared__ int cns[4];
  const int tid = threadIdx.x;
  const int wid = tid >> 6, lane = tid & 63;
  const int gid = blockIdx.x;
  const int b = gid >> 8;
  const int m = ((gid & 255) << 2) + wid;
  const float* supTb = supT ? supT + (size_t)b * Npts * 32 : nullptr;
  attn_body<K>(xyz, pf, supTb, cidx, idxS, cntS, wq, wk, wv, wo, outA,
               b, m, wid, lane, tid, WqL, WkL, WvL, WoL, xv, qv, yb, ov, cns);
}

// ---- K4b: combined both-scale attn (blocks 0..1023 = s0, 1024..2047 = s1) ----
__global__ __launch_bounds__(256) void attn_comb_kernel(
    const float* __restrict__ xyz, const float* __restrict__ pf,
    const float* __restrict__ supT, const int* __restrict__ cidx,
    const unsigned short* __restrict__ idx0, const int* __restrict__ cnt0,
    const unsigned short* __restrict__ idx1, const int* __restrict__ cnt1,
    const float* __restrict__ wq0, const float* __restrict__ wk0,
    const float* __restrict__ wv0, const float* __restrict__ wo0,
    const float* __restrict__ wq1, const float* __restrict__ wk1,
    const float* __restrict__ wv1, const float* __restrict__ wo1,
    __hip_bfloat16* __restrict__ attn0, __hip_bfloat16* __restrict__ attn1) {
  __shared__ float WqL[64*33], WkL[64*33], WvL[64*33], WoL[32*65];
  __shared__ float xv[4][32];
  __shared__ float qv[4][64];
  __shared__ float yb[4][2][32];
  __shared__ float ov[4][64];
  __shared__ int cns[4];
  const int tid = threadIdx.x;
  const int wid = tid >> 6, lane = tid & 63;
  const int s = blockIdx.x >> 10;
  const int gid = blockIdx.x & 1023;
  const int b = gid >> 8;
  const int m = ((gid & 255) << 2) + wid;
  const float* supTb = supT + (size_t)b * Npts * 32;
  if (s == 0)
    attn_body<32>(xyz, pf, supTb, cidx, idx0, cnt0, wq0, wk0, wv0, wo0, attn0,
                  b, m, wid, lane, tid, WqL, WkL, WvL, WoL, xv, qv, yb, ov, cns);
  else
    attn_body<64>(xyz, pf, supTb, cidx, idx1, cnt1, wq1, wk1, wv1, wo1, attn1,
                  b, m, wid, lane, tid, WqL, WkL, WvL, WoL, xv, qv, yb, ov, cns);
}

// ---- conv0 body ----
__device__ __forceinline__ void conv0_body(
    const __hip_bfloat16* inA, const float* w0, const float* b0,
    __hip_bfloat16* z0, float* ssum, float* ssq, int idx, int tid) {
  int m = idx & (Mc - 1);
  int r = (idx >> 10) & 63;
  int b = idx >> 16;
  float acc = b0[r];
#pragma unroll
  for (int c = 0; c < 32; ++c)
    acc = fmaf(w0[r*32 + c], __bfloat162float(inA[((size_t)b*32 + c)*Mc + m]), acc);
  z0[((size_t)b*64 + r)*Mc + m] = __float2bfloat16(acc);
  float s = acc, q = acc * acc;
#pragma unroll
  for (int d = 32; d; d >>= 1) { s += __shfl_down(s, d, 64); q += __shfl_down(q, d, 64); }
  if ((tid & 63) == 0) { atomicAdd(&ssum[r], s); atomicAdd(&ssq[r], q); }
}

__global__ __launch_bounds__(256) void conv0_kernel(
    const __hip_bfloat16* __restrict__ inA, const float* __restrict__ w0,
    const float* __restrict__ b0, __hip_bfloat16* __restrict__ z0,
    float* __restrict__ ssum, float* __restrict__ ssq) {
  conv0_body(inA, w0, b0, z0, ssum, ssq, blockIdx.x * 256 + threadIdx.x, threadIdx.x);
}

__global__ __launch_bounds__(256) void conv0_comb_kernel(
    const __hip_bfloat16* __restrict__ attn0, const __hip_bfloat16* __restrict__ attn1,
    const float* __restrict__ w00, const float* __restrict__ b00,
    const float* __restrict__ w01, const float* __restrict__ b01,
    __hip_bfloat16* __restrict__ z00, __hip_bfloat16* __restrict__ z01,
    float* __restrict__ st) {
  int s = blockIdx.x >> 10;
  int idx = (blockIdx.x & 1023) * 256 + threadIdx.x;
  float* stS = st + (size_t)s * 384;
  if (s == 0) conv0_body(attn0, w00, b00, z00, stS, stS + 64, idx, threadIdx.x);
  else        conv0_body(attn1, w01, b01, z01, stS, stS + 64, idx, threadIdx.x);
}

// ---- conv1 stats body ----
__device__ __forceinline__ void conv1_stats_body(
    const __hip_bfloat16* z0, const float* ssum0, const float* ssq0,
    const float* g0, const float* t0, const float* w1, const float* b1,
    float* z1, float* ssum1, float* ssq1, int idx, int tid) {
  __shared__ float A0s[64], B0s[64];
  if (tid < 64) {
    float mu = ssum0[tid] * (1.0f/4096.0f);
    float var = ssq0[tid] * (1.0f/4096.0f) - mu * mu;
    if (var < 0.f) var = 0.f;
    float a = g0[tid] * rsqrtf(var + BN_EPS);
    A0s[tid] = a;
    B0s[tid] = t0[tid] - mu * a;
  }
  __syncthreads();
  int m = idx & (Mc - 1);
  int r2 = (idx >> 10) & 127;
  int b = idx >> 17;
  float acc = b1[r2];
#pragma unroll 8
  for (int r = 0; r < 64; ++r) {
    float u = fmaf(__bfloat162float(z0[((size_t)b*64 + r)*Mc + m]), A0s[r], B0s[r]);
    u = u > 0.f ? u : SLOPE * u;
    acc = fmaf(w1[r2*64 + r], u, acc);
  }
  if (z1) z1[idx] = acc;
  float s = acc, q = acc * acc;
#pragma unroll
  for (int d = 32; d; d >>= 1) { s += __shfl_down(s, d, 64); q += __shfl_down(q, d, 64); }
  if ((tid & 63) == 0) { atomicAdd(&ssum1[r2], s); atomicAdd(&ssq1[r2], q); }
}

__global__ __launch_bounds__(256) void conv1_stats_kernel(
    const __hip_bfloat16* __restrict__ z0,
    const float* __restrict__ ssum0, const float* __restrict__ ssq0,
    const float* __restrict__ g0, const float* __restrict__ t0,
    const float* __restrict__ w1, const float* __restrict__ b1,
    float* __restrict__ z1, float* __restrict__ ssum1, float* __restrict__ ssq1) {
  conv1_stats_body(z0, ssum0, ssq0, g0, t0, w1, b1, z1, ssum1, ssq1,
                   blockIdx.x * 256 + threadIdx.x, threadIdx.x);
}

__global__ __launch_bounds__(256) void conv1_stats_comb_kernel(
    const __hip_bfloat16* __restrict__ z00, const __hip_bfloat16* __restrict__ z01,
    const float* __restrict__ g00, const float* __restrict__ t00,
    const float* __restrict__ w10, const float* __restrict__ b10,
    const float* __restrict__ g01, const float* __restrict__ t01,
    const float* __restrict__ w11, const float* __restrict__ b11,
    float* __restrict__ z10, float* __restrict__ z11, float* __restrict__ st) {
  int s = blockIdx.x >> 11;
  int idx = (blockIdx.x & 2047) * 256 + threadIdx.x;
  float* stS = st + (size_t)s * 384;
  if (s == 0)
    conv1_stats_body(z00, stS, stS + 64, g00, t00, w10, b10, z10, stS + 128, stS + 256,
                     idx, threadIdx.x);
  else
    conv1_stats_body(z01, stS, stS + 64, g01, t01, w11, b11, z11, stS + 128, stS + 256,
                     idx, threadIdx.x);
}

// ---- conv1 write body (z1 path) ----
__device__ __forceinline__ void conv1_write_body(
    const float* z1, const float* ssum1, const float* ssq1,
    const float* g1, const float* t1, float* outAll, int chOff, int out_size,
    int idx, int tid) {
  __shared__ float ab1[2];
  int m = idx & (Mc - 1);
  int r2 = (idx >> 10) & 127;
  int b = idx >> 17;
  if (tid == 0) {
    float mu = ssum1[r2] * (1.0f/4096.0f);
    float var = ssq1[r2] * (1.0f/4096.0f) - mu * mu;
    if (var < 0.f) var = 0.f;
    float a = g1[r2] * rsqrtf(var + BN_EPS);
    ab1[0] = a;
    ab1[1] = t1[r2] - mu * a;
  }
  __syncthreads();
  float v = fmaf(z1[idx], ab1[0], ab1[1]);
  size_t oidx = 12288 + ((size_t)b*256 + chOff + r2)*Mc + m;
  if (oidx < (size_t)out_size) outAll[oidx] = sanf(v, 777.0f);
}

// fallback (recompute variant) — from R16, used only when z1 missing
__global__ __launch_bounds__(256) void conv1_write_kernel(
    const __hip_bfloat16* __restrict__ z0, const float* __restrict__ z1,
    const float* __restrict__ ssum0, const float* __restrict__ ssq0,
    const float* __restrict__ g0, const float* __restrict__ t0,
    const float* __restrict__ w1, const float* __restrict__ b1,
    const float* __restrict__ ssum1, const float* __restrict__ ssq1,
    const float* __restrict__ g1, const float* __restrict__ t1,
    float* __restrict__ outAll, int chOff, int out_size) {
  __shared__ float A0s[64], B0s[64];
  __shared__ float ab1[2];
  int tid = threadIdx.x;
  int idx = blockIdx.x * 256 + tid;
  int m = idx & (Mc - 1);
  int r2 = (idx >> 10) & 127;
  int b = idx >> 17;
  if (!z1 && tid < 64) {
    float mu = ssum0[tid] * (1.0f/4096.0f);
    float var = ssq0[tid] * (1.0f/4096.0f) - mu * mu;
    if (var < 0.f) var = 0.f;
    float a = g0[tid] * rsqrtf(var + BN_EPS);
    A0s[tid] = a;
    B0s[tid] = t0[tid] - mu * a;
  }
  if (tid == 0) {
    float mu = ssum1[r2] * (1.0f/4096.0f);
    float var = ssq1[r2] * (1.0f/4096.0f) - mu * mu;
    if (var < 0.f) var = 0.f;
    float a = g1[r2] * rsqrtf(var + BN_EPS);
    ab1[0] = a;
    ab1[1] = t1[r2] - mu * a;
  }
  __syncthreads();
  float acc;
  if (z1) {
    acc = z1[idx];
  } else {
    acc = b1[r2];
#pragma unroll 8
    for (int r = 0; r < 64; ++r) {
      float u = fmaf(__bfloat162float(z0[((size_t)b*64 + r)*Mc + m]), A0s[r], B0s[r]);
      u = u > 0.f ? u : SLOPE * u;
      acc = fmaf(w1[r2*64 + r], u, acc);
    }
  }
  float v = fmaf(acc, ab1[0], ab1[1]);
  size_t oidx = 12288 + ((size_t)b*256 + chOff + r2)*Mc + m;
  if (oidx < (size_t)out_size) outAll[oidx] = sanf(v, 777.0f);
}

__global__ __launch_bounds__(256) void conv1_write_comb_kernel(
    const float* __restrict__ z10, const float* __restrict__ z11,
    const float* __restrict__ g10, const float* __restrict__ t10,
    const float* __restrict__ g11, const float* __restrict__ t11,
    const float* __restrict__ st, float* __restrict__ outAll, int out_size) {
  int s = blockIdx.x >> 11;
  int idx = (blockIdx.x & 2047) * 256 + threadIdx.x;
  const float* stS = st + (size_t)s * 384;
  if (s == 0)
    conv1_write_body(z10, stS + 128, stS + 256, g10, t10, outAll, 0, out_size,
                     idx, threadIdx.x);
  else
    conv1_write_body(z11, stS + 128, stS + 256, g11, t11, outAll, 128, out_size,
                     idx, threadIdx.x);
}

extern "C" void kernel_launch(void* const* d_in, const int* in_sizes, int n_in,
                              void* d_out, int out_size, void* d_ws, size_t ws_size,
                              hipStream_t stream) {
  float* outb = (float*)d_out;
  int fillBlocks = (out_size + 255) / 256;
  if (n_in != 26 || in_sizes[0] != Bb*3*Npts || in_sizes[1] != Bb*29*Npts
      || in_sizes[2] != 2048) {
    fill_kernel<<<fillBlocks, 256, 0, stream>>>(outb, out_size, 7777.0f);
    return;
  }
  if (out_size != OUT_EXPECT) {
    fill_kernel<<<fillBlocks, 256, 0, stream>>>(outb, out_size, 23456.0f);
    return;
  }
  if (ws_size < WS_REQUIRED) {
    fill_kernel<<<fillBlocks, 256, 0, stream>>>(outb, out_size, 12345.0f);
    return;
  }
  const float* xyz = (const float*)d_in[0];
  const float* pf  = (const float*)d_in[1];
  char* ws = (char*)d_ws;
  int* cidx = (int*)(ws + OFF_CIDX);
  unsigned short* idx0 = (unsigned short*)(ws + OFF_IDX0);
  int* cnt0 = (int*)(ws + OFF_CNT0);
  unsigned short* idx1 = (unsigned short*)(ws + OFF_IDX1);
  int* cnt1 = (int*)(ws + OFF_CNT1);
  unsigned long long* fslots = (unsigned long long*)(ws + OFF_FSLOT);
  __hip_bfloat16* attn0 = (__hip_bfloat16*)(ws + OFF_ATTN);
  __hip_bfloat16* z00 = (__hip_bfloat16*)(ws + OFF_Z0);
  const bool fused = (ws_size >= WS_T_REQUIRED);
  const bool comb = (ws_size >= WS_EXT_REQUIRED);
  float* z10 = (ws_size >= WS_Z1_REQUIRED) ? (float*)(ws + OFF_Z1) : nullptr;
  float* supT = fused ? (float*)(ws + OFF_SUPT) : nullptr;
  unsigned int* gcnt = (unsigned int*)(ws + OFF_GCNT);
  unsigned int* gent = (unsigned int*)(ws + OFF_GENT);
  __hip_bfloat16* attn1 = comb ? (__hip_bfloat16*)(ws + OFF_ATTN1) : nullptr;
  __hip_bfloat16* z01 = comb ? (__hip_bfloat16*)(ws + OFF_Z01) : nullptr;
  float* z11 = comb ? (float*)(ws + OFF_Z11) : nullptr;
  float* st = (float*)(ws + OFF_STATS);

  // weight pointers
  const float *W[24];
  for (int i = 0; i < 24; ++i) W[i] = (const float*)d_in[2 + i];
  // per scale s: W[s*12 + {0:aq,1:ak,2:av,3:ao,4:w0,5:b0,6:g0,7:t0,8:w1,9:b1,10:g1,11:t1}]

  hipMemsetAsync(ws, 0, ZERO_BYTES, stream);
  hipMemsetAsync(ws + OFF_FSLOT, 0, FSLOT_BYTES, stream);
  if (fused) {
    hipMemsetAsync(ws + OFF_CIDX, 0xFF, Bb * Mc * 4, stream);
    buildT_kernel<<<Bb*Npts/256, 256, 0, stream>>>(xyz, pf, supT);
    fps_ball_kernel<<<192, 512, 0, stream>>>(xyz, pf, supT, (unsigned int*)cidx,
                                             fslots, gcnt, gent);
    ballpost_kernel<<<16, 256, 0, stream>>>(gcnt, gent, idx0, cnt0, idx1, cnt1);
  } else {
    fps_kernel<<<Bb*NBLK, 512, 0, stream>>>(xyz, pf, supT, cidx, fslots);
    ball_kernel<<<Bb*64, 256, 0, stream>>>(xyz, pf, cidx, idx0, cnt0, idx1, cnt1);
  }

  if (comb) {
    attn_comb_kernel<<<2048, 256, 0, stream>>>(xyz, pf, supT, cidx,
        idx0, cnt0, idx1, cnt1,
        W[0], W[1], W[2], W[3], W[12], W[13], W[14], W[15], attn0, attn1);
    conv0_comb_kernel<<<2048, 256, 0, stream>>>(attn0, attn1,
        W[4], W[5], W[16], W[17], z00, z01, st);
    conv1_stats_comb_kernel<<<4096, 256, 0, stream>>>(z00, z01,
        W[6], W[7], W[8], W[9], W[18], W[19], W[20], W[21], z10, z11, st);
    conv1_write_comb_kernel<<<4096, 256, 0, stream>>>(z10, z11,
        W[10], W[11], W[22], W[23], st, outb, out_size);
  } else {
    for (int s = 0; s < 2; ++s) {
      const float *aq = W[s*12+0], *ak = W[s*12+1], *av = W[s*12+2], *ao = W[s*12+3];
      const float *w0 = W[s*12+4], *b0 = W[s*12+5], *g0 = W[s*12+6], *t0 = W[s*12+7];
      const float *w1 = W[s*12+8], *b1 = W[s*12+9], *g1 = W[s*12+10], *t1 = W[s*12+11];
      float* stS = st + (size_t)s*384;
      float *sum0 = stS, *sq0 = stS + 64, *sum1 = stS + 128, *sq1 = stS + 256;
      if (s == 0)
        attn_kernel<32><<<Bb*Mc/4, 256, 0, stream>>>(xyz, pf, supT, cidx, idx0, cnt0,
                                                     aq, ak, av, ao, attn0);
      else
        attn_kernel<64><<<Bb*Mc/4, 256, 0, stream>>>(xyz, pf, supT, cidx, idx1, cnt1,
                                                     aq, ak, av, ao, attn0);
      conv0_kernel<<<Bb*64*Mc/256, 256, 0, stream>>>(attn0, w0, b0, z00, sum0, sq0);
      conv1_stats_kernel<<<Bb*128*Mc/256, 256, 0, stream>>>(z00, sum0, sq0, g0, t0,
                                                            w1, b1, z10, sum1, sq1);
      conv1_write_kernel<<<Bb*128*Mc/256, 256, 0, stream>>>(z00, z10, sum0, sq0, g0, t0,
                                                            w1, b1, sum1, sq1, g1, t1,
                                                            outb, s*128, out_size);
    }
  }
  gather_kernel<<<48, 256, 0, stream>>>(xyz, cidx, outb, out_size);
}